// Round 5
// baseline (455.518 us; speedup 1.0000x reference)
//
#include <hip/hip_runtime.h>

// Problem constants (from reference)
constexpr int NN = 50000;   // nodes
constexpr int NE = 800000;  // edges
constexpr int CI = 16;      // in channels
constexpr int CO = 64;      // out channels
constexpr int DD = 7;       // decoder dim

// h-side node arrays are stored as 2 SoA planes of 32 channels (64B/node) so a
// half-channel prop pass has a 3.2 MB working set that fits per-XCD L2 (4 MiB).
constexpr int PS = NN * 32;  // plane stride in bf16 elements

typedef __bf16 bf16x8 __attribute__((ext_vector_type(8)));
typedef float  f32x4  __attribute__((ext_vector_type(4)));

__device__ inline float blo(unsigned u) { return __uint_as_float(u << 16); }
__device__ inline float bhi(unsigned u) { return __uint_as_float(u & 0xffff0000u); }

// ================= fused: edge histograms(+rank) + bf16 casts + B-prep =================

constexpr int EB = (NE + 255) / 256;           // 3125
constexpr int XOCT = NN * CI / 8;              // 100000 bf16x8 octets in x
constexpr int HOCT = NN * CO / 8;              // 400000 octets in h0
constexpr int CB = (XOCT + HOCT + 255) / 256;  // 1954

__global__ void __launch_bounds__(256) k_deg_cast_prep(
    const int* __restrict__ src, const int* __restrict__ dst, const float* __restrict__ ew,
    float* __restrict__ deg, int* __restrict__ count, int* __restrict__ rank,
    const float* __restrict__ x, const float* __restrict__ h0,
    __bf16* __restrict__ x_bf, __bf16* __restrict__ h0_bf,
    const float* __restrict__ Wx, const float* __restrict__ Wh,
    const float* __restrict__ bx, const float* __restrict__ bh,
    bf16x8* __restrict__ BfragZR, bf16x8* __restrict__ BfragHT, float* __restrict__ biasC) {
    int b = blockIdx.x;
    if (b < EB) {
        int e = b * 256 + threadIdx.x;
        if (e >= NE) return;
        int s = src[e], d = dst[e];
        float w = (s == d) ? 0.f : ew[e];
        atomicAdd(&deg[s], w);
        rank[e] = atomicAdd(&count[d], 1);   // rank doubles as placement slot
    } else if (b < EB + CB) {
        int t = (b - EB) * 256 + threadIdx.x;  // octet index
        const float* sp; __bf16* dp;
        if (t < XOCT) { sp = x + t * 8; dp = x_bf + t * 8; }
        else if (t < XOCT + HOCT) {
            int u = t - XOCT;
            int n = u >> 3, d8 = u & 7;                 // which 8-ch group of node n
            sp = h0 + (size_t)n * 64 + d8 * 8;
            dp = h0_bf + (d8 >> 2) * PS + (size_t)n * 32 + (d8 & 3) * 8;  // SoA plane
        } else return;
        float4 a = *(const float4*)sp;
        float4 c = *(const float4*)(sp + 4);
        bf16x8 o;
        o[0] = (__bf16)a.x; o[1] = (__bf16)a.y; o[2] = (__bf16)a.z; o[3] = (__bf16)a.w;
        o[4] = (__bf16)c.x; o[5] = (__bf16)c.y; o[6] = (__bf16)c.z; o[7] = (__bf16)c.w;
        *(bf16x8*)dp = o;
    } else {
        int tid = (b - EB - CB) * 256 + threadIdx.x;
        if (tid < 6144) {
            int e = tid, gate, n, kk, l;
            if (e < 4096) {
                int t = e >> 9, rem = e & 511;
                kk = rem >> 6; l = rem & 63;
                n = t * 16 + (l & 15);
                gate = n >> 6;
            } else {
                int e2 = e - 4096;
                int t = e2 >> 9, rem = e2 & 511;
                kk = rem >> 6; l = rem & 63;
                n = t * 16 + (l & 15);
                gate = 2;
            }
            int co = n & 63;
            int k0 = kk * 32 + (l >> 4) * 8;
            bf16x8 f;
#pragma unroll
            for (int j = 0; j < 8; j++) {
                int k = k0 + j;
                float w = 0.f;
                if (k < 48) w = Wx[((gate * 3 + (k >> 4)) * 16 + (k & 15)) * 64 + co];
                else if (k < 240) { int kh = k - 48; w = Wh[((gate * 3 + (kh >> 6)) * 64 + (kh & 63)) * 64 + co]; }
                f[j] = (__bf16)w;
            }
            if (e < 4096) BfragZR[e] = f; else BfragHT[e - 4096] = f;
        } else if (tid < 6144 + 192) {
            int i = tid - 6144;
            biasC[i] = bx[i] + bh[i];
        }
    }
}

// ============================= scan =============================

__global__ void k_scan1(const int* __restrict__ count, int* __restrict__ S, int* __restrict__ bsums) {
    __shared__ int ts[256];
    int tid = threadIdx.x;
    int base = blockIdx.x * 1024;
    int vals[4]; int s = 0;
#pragma unroll
    for (int j = 0; j < 4; j++) {
        int idx = base + tid * 4 + j;
        int v = (idx < NN) ? count[idx] : 0;
        s += v; vals[j] = s;
    }
    ts[tid] = s;
    __syncthreads();
    for (int off = 1; off < 256; off <<= 1) {
        int v = (tid >= off) ? ts[tid - off] : 0;
        __syncthreads();
        ts[tid] += v;
        __syncthreads();
    }
    int prev = (tid > 0) ? ts[tid - 1] : 0;
#pragma unroll
    for (int j = 0; j < 4; j++) {
        int idx = base + tid * 4 + j;
        if (idx < NN) S[idx] = vals[j] + prev;
    }
    if (tid == 255) bsums[blockIdx.x] = ts[255];
}

__global__ void k_scan2(int* __restrict__ bsums, int nb) {
    if (threadIdx.x == 0 && blockIdx.x == 0) {
        int run = 0;
        for (int i = 0; i < nb; i++) { int v = bsums[i]; bsums[i] = run; run += v; }
    }
}

// rowptr from scan pieces; dinv = deg > 0 ? rsqrt(deg) : 0 (in place on deg)
__global__ void k_scan3_dinv(const int* __restrict__ S, const int* __restrict__ count,
                             const int* __restrict__ bsums,
                             int* __restrict__ rowptr, float* __restrict__ deg) {
    int i = blockIdx.x * 256 + threadIdx.x;
    if (i >= NN) return;
    int tot = S[i] + bsums[i >> 10];
    rowptr[i + 1] = tot;
    if (i == 0) rowptr[0] = 0;
    float d = deg[i];
    deg[i] = (d > 0.f) ? (1.f / sqrtf(d)) : 0.f;
}

// atomic-free CSR placement; stores w' = dinv[src]*w (the -dinv[dst] factor is
// applied per-node inside the prop kernels, killing the dinv[dst] gather here)
__global__ void k_place(const int* __restrict__ src, const int* __restrict__ dst,
                        const float* __restrict__ ew, const int* __restrict__ rank,
                        const float* __restrict__ dinv, const int* __restrict__ rowptr,
                        int2* __restrict__ csr_ew) {
    int e = blockIdx.x * 256 + threadIdx.x;
    if (e >= NE) return;
    int s = src[e], d = dst[e];
    float w = (s == d) ? 0.f : ew[e];
    float wp = dinv[s] * w;
    csr_ew[rowptr[d] + rank[e]] = make_int2(s, __float_as_int(wp));
}

// ============================= propagation (bf16, SoA planes) =============================
// out[n] = (-dinv[n]*scale) * sum_{e in row n} w'_e * v[src_e]  (- sub[n] if sub)

// 32-channel plane pass: wave per node; 16 edges in flight, 4 lanes x 16B per row.
__global__ void __launch_bounds__(256) k_prop32(
    const __bf16* __restrict__ vplane, const __bf16* __restrict__ subplane,
    const float* __restrict__ dinv, float scale,
    const int* __restrict__ rowptr, const int2* __restrict__ ew,
    __bf16* __restrict__ outplane) {
    int n = blockIdx.x * 4 + (threadIdx.x >> 6);
    if (n >= NN) return;
    int lane = threadIdx.x & 63;
    int j = lane >> 2, cg = lane & 3;
    int beg = rowptr[n], end = rowptr[n + 1];
    float acc[8] = {0.f, 0.f, 0.f, 0.f, 0.f, 0.f, 0.f, 0.f};
    for (int e = beg + j; e < end; e += 16) {
        int2 p = ew[e];
        float w = __int_as_float(p.y);
        uint4 u = *(const uint4*)((const char*)vplane + ((size_t)p.x * 64 + cg * 16));
        acc[0] += w * blo(u.x); acc[1] += w * bhi(u.x);
        acc[2] += w * blo(u.y); acc[3] += w * bhi(u.y);
        acc[4] += w * blo(u.z); acc[5] += w * bhi(u.z);
        acc[6] += w * blo(u.w); acc[7] += w * bhi(u.w);
    }
#pragma unroll
    for (int m = 4; m <= 32; m <<= 1) {
#pragma unroll
        for (int i = 0; i < 8; i++) acc[i] += __shfl_xor(acc[i], m, 64);
    }
    if (lane < 4) {
        float f = -dinv[n] * scale;
        float o[8];
        if (subplane) {
            uint4 su = *(const uint4*)((const char*)subplane + ((size_t)n * 64 + lane * 16));
            o[0] = f * acc[0] - blo(su.x); o[1] = f * acc[1] - bhi(su.x);
            o[2] = f * acc[2] - blo(su.y); o[3] = f * acc[3] - bhi(su.y);
            o[4] = f * acc[4] - blo(su.z); o[5] = f * acc[5] - bhi(su.z);
            o[6] = f * acc[6] - blo(su.w); o[7] = f * acc[7] - bhi(su.w);
        } else {
#pragma unroll
            for (int i = 0; i < 8; i++) o[i] = f * acc[i];
        }
        bf16x8 st;
#pragma unroll
        for (int i = 0; i < 8; i++) st[i] = (__bf16)o[i];
        *(bf16x8*)(outplane + (size_t)n * 32 + lane * 8) = st;
    }
}

// C=16 x-pass (1.6 MB working set, already L2-resident): 32 edges in flight.
__global__ void __launch_bounds__(256) k_prop16(
    const __bf16* __restrict__ v, const __bf16* __restrict__ sub,
    const float* __restrict__ dinv, float scale,
    const int* __restrict__ rowptr, const int2* __restrict__ ew, __bf16* __restrict__ out) {
    int n = blockIdx.x * 4 + (threadIdx.x >> 6);
    if (n >= NN) return;
    int lane = threadIdx.x & 63;
    int j = lane >> 1, cg = lane & 1;
    int beg = rowptr[n], end = rowptr[n + 1];
    float acc[8] = {0.f, 0.f, 0.f, 0.f, 0.f, 0.f, 0.f, 0.f};
    for (int e = beg + j; e < end; e += 32) {
        int2 p = ew[e];
        float w = __int_as_float(p.y);
        uint4 u = *(const uint4*)((const char*)v + ((size_t)p.x * 32 + cg * 16));
        acc[0] += w * blo(u.x); acc[1] += w * bhi(u.x);
        acc[2] += w * blo(u.y); acc[3] += w * bhi(u.y);
        acc[4] += w * blo(u.z); acc[5] += w * bhi(u.z);
        acc[6] += w * blo(u.w); acc[7] += w * bhi(u.w);
    }
#pragma unroll
    for (int m = 2; m <= 32; m <<= 1) {
#pragma unroll
        for (int i = 0; i < 8; i++) acc[i] += __shfl_xor(acc[i], m, 64);
    }
    if (lane < 2) {
        float f = -dinv[n] * scale;
        float o[8];
        if (sub) {
            uint4 su = *(const uint4*)((const char*)sub + ((size_t)n * 32 + lane * 16));
            o[0] = f * acc[0] - blo(su.x); o[1] = f * acc[1] - bhi(su.x);
            o[2] = f * acc[2] - blo(su.y); o[3] = f * acc[3] - bhi(su.y);
            o[4] = f * acc[4] - blo(su.z); o[5] = f * acc[5] - bhi(su.z);
            o[6] = f * acc[6] - blo(su.w); o[7] = f * acc[7] - bhi(su.w);
        } else {
#pragma unroll
            for (int i = 0; i < 8; i++) o[i] = f * acc[i];
        }
        bf16x8 st;
#pragma unroll
        for (int i = 0; i < 8; i++) st[i] = (__bf16)o[i];
        *(bf16x8*)(out + (size_t)n * 16 + lane * 8) = st;
    }
}

// ============================= MFMA dense gates =============================
// Logical A row (K=256): [x(16)|Tx1(16)|Tx2(16)|H(64)|H1(64)|H2(64)|pad(16)], bf16.
// H-side arrays are 2-plane SoA.

__device__ inline bf16x8 load_a_bf(int c, int m,
                                   const __bf16* __restrict__ xb, const __bf16* __restrict__ t1,
                                   const __bf16* __restrict__ t2, const __bf16* __restrict__ hb,
                                   const __bf16* __restrict__ h1, const __bf16* __restrict__ h2) {
    if (c >= 30) {
        bf16x8 a;
#pragma unroll
        for (int j = 0; j < 8; j++) a[j] = (__bf16)0.f;
        return a;
    }
    if (c < 6) {
        const __bf16* base = (c < 2) ? xb : ((c < 4) ? t1 : t2);
        return *(const bf16x8*)(base + (size_t)m * 16 + (c & 1) * 8);
    }
    int d = c - 6;
    const __bf16* base = (d < 8) ? hb : ((d < 16) ? h1 : h2);
    int dd = d & 7;
    return *(const bf16x8*)(base + (dd >> 2) * PS + (size_t)m * 32 + (dd & 3) * 8);
}

// z and r gates: one wave per 16-node tile, 128 output cols (8 out-tiles).
__global__ void __launch_bounds__(256) k_mfma_zr(
    const __bf16* __restrict__ xb, const __bf16* __restrict__ t1, const __bf16* __restrict__ t2,
    const __bf16* __restrict__ hb, const __bf16* __restrict__ h1, const __bf16* __restrict__ h2,
    const bf16x8* __restrict__ Bfrag, const float* __restrict__ biasC,
    const float* __restrict__ h0, __bf16* __restrict__ z_bf, __bf16* __restrict__ hr_bf) {
    int wv = (blockIdx.x * 256 + threadIdx.x) >> 6;
    if (wv >= NN / 16) return;
    int lane = threadIdx.x & 63;
    int q = lane >> 4, r16 = lane & 15;
    int ma = wv * 16 + r16;
    f32x4 acc[8];
#pragma unroll
    for (int t = 0; t < 8; t++) acc[t] = (f32x4){0.f, 0.f, 0.f, 0.f};
#pragma unroll
    for (int kk = 0; kk < 8; kk++) {
        bf16x8 a = load_a_bf(kk * 4 + q, ma, xb, t1, t2, hb, h1, h2);
#pragma unroll
        for (int t = 0; t < 8; t++)
            acc[t] = __builtin_amdgcn_mfma_f32_16x16x32_bf16(a, Bfrag[(t * 8 + kk) * 64 + lane], acc[t], 0, 0, 0);
    }
    int mbase = wv * 16 + q * 4;
#pragma unroll
    for (int t = 0; t < 8; t++) {
        int co = t * 16 + r16;      // 0..127
        float bias = biasC[co];
        int col = co & 63;
#pragma unroll
        for (int reg = 0; reg < 4; reg++) {
            int mm = mbase + reg;
            float p = acc[t][reg] + bias;
            float s = 1.f / (1.f + __expf(-p));
            if (t < 4) z_bf[(size_t)mm * 64 + col] = (__bf16)s;
            else       hr_bf[(col >> 5) * PS + (size_t)mm * 32 + (col & 31)] =
                           (__bf16)(s * h0[(size_t)mm * 64 + col]);
        }
    }
}

// htilde gate + GRU combine + fused decoder: wave per 16-node tile.
__global__ void __launch_bounds__(256) k_mfma_ht(
    const __bf16* __restrict__ xb, const __bf16* __restrict__ t1, const __bf16* __restrict__ t2,
    const __bf16* __restrict__ hrb, const __bf16* __restrict__ r1, const __bf16* __restrict__ r2,
    const bf16x8* __restrict__ Bfrag, const float* __restrict__ biasC,
    const __bf16* __restrict__ z_bf, const float* __restrict__ h0,
    const float* __restrict__ Wlin, const float* __restrict__ blin,
    float* __restrict__ hout, float* __restrict__ yout) {
    int wv = (blockIdx.x * 256 + threadIdx.x) >> 6;
    if (wv >= NN / 16) return;
    int lane = threadIdx.x & 63;
    int q = lane >> 4, r16 = lane & 15;
    int ma = wv * 16 + r16;
    f32x4 acc[4];
#pragma unroll
    for (int t = 0; t < 4; t++) acc[t] = (f32x4){0.f, 0.f, 0.f, 0.f};
#pragma unroll
    for (int kk = 0; kk < 8; kk++) {
        bf16x8 a = load_a_bf(kk * 4 + q, ma, xb, t1, t2, hrb, r1, r2);
#pragma unroll
        for (int t = 0; t < 4; t++)
            acc[t] = __builtin_amdgcn_mfma_f32_16x16x32_bf16(a, Bfrag[(t * 8 + kk) * 64 + lane], acc[t], 0, 0, 0);
    }
    int mbase = wv * 16 + q * 4;
    float hbuf[4][4];
#pragma unroll
    for (int t = 0; t < 4; t++) {
        int co = t * 16 + r16;   // 0..63
        float bias = biasC[128 + co];
#pragma unroll
        for (int reg = 0; reg < 4; reg++) {
            int mm = mbase + reg;
            float p = acc[t][reg] + bias;
            float htl = tanhf(p);
            float zv = (float)z_bf[(size_t)mm * 64 + co];
            float h0v = h0[(size_t)mm * 64 + co];
            float hn = zv * h0v + (1.f - zv) * htl;
            hout[(size_t)mm * 64 + co] = hn;
            hbuf[t][reg] = hn;
        }
    }
    // fused y = relu(h) @ Wlin + blin : partials per lane, reduce over the 16-lane group
    float ya[4][DD];
#pragma unroll
    for (int reg = 0; reg < 4; reg++)
#pragma unroll
        for (int d = 0; d < DD; d++) ya[reg][d] = 0.f;
#pragma unroll
    for (int t = 0; t < 4; t++) {
        int cb = (t * 16 + r16) * DD;
        float wl[DD];
#pragma unroll
        for (int d = 0; d < DD; d++) wl[d] = Wlin[cb + d];
#pragma unroll
        for (int reg = 0; reg < 4; reg++) {
            float rh = fmaxf(hbuf[t][reg], 0.f);
#pragma unroll
            for (int d = 0; d < DD; d++) ya[reg][d] += rh * wl[d];
        }
    }
#pragma unroll
    for (int m = 1; m <= 8; m <<= 1) {
#pragma unroll
        for (int reg = 0; reg < 4; reg++)
#pragma unroll
            for (int d = 0; d < DD; d++) ya[reg][d] += __shfl_xor(ya[reg][d], m, 64);
    }
    if (r16 < DD) {
        float b = blin[r16];
#pragma unroll
        for (int reg = 0; reg < 4; reg++) {
            float v = (r16 == 0) ? ya[reg][0] : (r16 == 1) ? ya[reg][1] : (r16 == 2) ? ya[reg][2]
                    : (r16 == 3) ? ya[reg][3] : (r16 == 4) ? ya[reg][4] : (r16 == 5) ? ya[reg][5]
                    : ya[reg][6];
            yout[(size_t)(mbase + reg) * DD + r16] = v + b;
        }
    }
}

// ============================= launch =============================

extern "C" void kernel_launch(void* const* d_in, const int* in_sizes, int n_in,
                              void* d_out, int out_size, void* d_ws, size_t ws_size,
                              hipStream_t stream) {
    (void)in_sizes; (void)n_in; (void)out_size; (void)ws_size;
    const float* x    = (const float*)d_in[0];
    const int*   eidx = (const int*)d_in[1];
    const float* ew   = (const float*)d_in[2];
    const float* h0   = (const float*)d_in[3];
    const float* Wx   = (const float*)d_in[4];
    const float* Wh   = (const float*)d_in[5];
    const float* bx   = (const float*)d_in[6];
    const float* bh   = (const float*)d_in[7];
    const float* Wlin = (const float*)d_in[8];
    const float* blin = (const float*)d_in[9];
    const int* src = eidx;
    const int* dst = eidx + NE;

    char* ws = (char*)d_ws;
    size_t off = 0;
    auto alloc = [&](size_t nbytes) -> void* {
        void* p = ws + off;
        off += (nbytes + 255) & ~(size_t)255;
        return p;
    };
    float*  dinv    = (float*)alloc(NN * 4);        // deg, then dinv in-place
    int*    count   = (int*)alloc(NN * 4);
    int*    S       = (int*)alloc(NN * 4);
    int*    rowptr  = (int*)alloc((NN + 1) * 4);
    int*    bsums   = (int*)alloc(64 * 4);
    int*    rank    = (int*)alloc((size_t)NE * 4);
    int2*   csr_ew  = (int2*)alloc((size_t)NE * 8);
    __bf16* x_bf    = (__bf16*)alloc((size_t)NN * CI * 2);
    __bf16* h0_bf   = (__bf16*)alloc((size_t)NN * CO * 2);   // 2 planes
    __bf16* Tx1     = (__bf16*)alloc((size_t)NN * CI * 2);
    __bf16* Tx2     = (__bf16*)alloc((size_t)NN * CI * 2);
    __bf16* Th1     = (__bf16*)alloc((size_t)NN * CO * 2);   // 2 planes
    __bf16* Th2     = (__bf16*)alloc((size_t)NN * CO * 2);   // 2 planes
    __bf16* hr_bf   = (__bf16*)alloc((size_t)NN * CO * 2);   // 2 planes
    __bf16* z_bf    = (__bf16*)alloc((size_t)NN * CO * 2);   // flat
    bf16x8* BfragZR = (bf16x8*)alloc(4096 * 16);
    bf16x8* BfragHT = (bf16x8*)alloc(2048 * 16);
    float*  biasC   = (float*)alloc(192 * 4);

    float* hout = (float*)d_out;
    float* yout = hout + (size_t)NN * CO;

    constexpr int NB = (NN + 1023) / 1024;   // scan chunks
    const int NBLK = (NN + 255) / 256;
    const int PROPB = (NN + 3) / 4;          // 4 waves/block, wave per node
    const int GEMMB = (NN / 16 * 64 + 255) / 256;

    hipMemsetAsync(dinv, 0, NN * 4, stream);
    hipMemsetAsync(count, 0, NN * 4, stream);

    k_deg_cast_prep<<<EB + CB + 25, 256, 0, stream>>>(
        src, dst, ew, dinv, count, rank, x, h0, x_bf, h0_bf,
        Wx, Wh, bx, bh, BfragZR, BfragHT, biasC);
    k_scan1<<<NB, 256, 0, stream>>>(count, S, bsums);
    k_scan2<<<1, 64, 0, stream>>>(bsums, NB);
    k_scan3_dinv<<<NBLK, 256, 0, stream>>>(S, count, bsums, rowptr, dinv);
    k_place<<<EB, 256, 0, stream>>>(src, dst, ew, rank, dinv, rowptr, csr_ew);

    // stage 1: Th1 = P(h0) [two planes], Tx1 = P(x)
    k_prop32<<<PROPB, 256, 0, stream>>>(h0_bf,      nullptr, dinv, 1.f, rowptr, csr_ew, Th1);
    k_prop32<<<PROPB, 256, 0, stream>>>(h0_bf + PS, nullptr, dinv, 1.f, rowptr, csr_ew, Th1 + PS);
    k_prop16<<<PROPB, 256, 0, stream>>>(x_bf, nullptr, dinv, 1.f, rowptr, csr_ew, Tx1);
    // stage 2: Th2 = 2P(Th1) - h0, Tx2 = 2P(Tx1) - x
    k_prop32<<<PROPB, 256, 0, stream>>>(Th1,      h0_bf,      dinv, 2.f, rowptr, csr_ew, Th2);
    k_prop32<<<PROPB, 256, 0, stream>>>(Th1 + PS, h0_bf + PS, dinv, 2.f, rowptr, csr_ew, Th2 + PS);
    k_prop16<<<PROPB, 256, 0, stream>>>(Tx1, x_bf, dinv, 2.f, rowptr, csr_ew, Tx2);

    // z and r gates (r fused into hr = r*h0)
    k_mfma_zr<<<GEMMB, 256, 0, stream>>>(x_bf, Tx1, Tx2, h0_bf, Th1, Th2,
                                         BfragZR, biasC, h0, z_bf, hr_bf);
    // propagate hr (reuse Th1/Th2 as Thr1/Thr2)
    k_prop32<<<PROPB, 256, 0, stream>>>(hr_bf,      nullptr, dinv, 1.f, rowptr, csr_ew, Th1);
    k_prop32<<<PROPB, 256, 0, stream>>>(hr_bf + PS, nullptr, dinv, 1.f, rowptr, csr_ew, Th1 + PS);
    k_prop32<<<PROPB, 256, 0, stream>>>(Th1,      hr_bf,      dinv, 2.f, rowptr, csr_ew, Th2);
    k_prop32<<<PROPB, 256, 0, stream>>>(Th1 + PS, hr_bf + PS, dinv, 2.f, rowptr, csr_ew, Th2 + PS);
    // htilde gate + GRU combine + fused decoder -> h, y
    k_mfma_ht<<<GEMMB, 256, 0, stream>>>(x_bf, Tx1, Tx2, hr_bf, Th1, Th2,
                                         BfragHT, biasC, z_bf, h0, Wlin, blin, hout, yout);
}

// Round 6
// 373.833 us; speedup vs baseline: 1.2185x; 1.2185x over previous
//
#include <hip/hip_runtime.h>

// Problem constants (from reference)
constexpr int NN = 50000;   // nodes
constexpr int NE = 800000;  // edges
constexpr int CI = 16;      // in channels
constexpr int CO = 64;      // out channels
constexpr int DD = 7;       // decoder dim

typedef __bf16 bf16x8 __attribute__((ext_vector_type(8)));
typedef float  f32x4  __attribute__((ext_vector_type(4)));

__device__ inline float blo(unsigned u) { return __uint_as_float(u << 16); }
__device__ inline float bhi(unsigned u) { return __uint_as_float(u & 0xffff0000u); }

// ================= fused: edge histograms(+rank) + bf16 casts + B-prep =================
// Atomic counters are padded to one per 64B line (stride 16) to break same-line
// RMW serialization at the memory-side coherence point.

constexpr int EB = (NE + 255) / 256;           // 3125
constexpr int XOCT = NN * CI / 8;              // 100000 bf16x8 octets in x
constexpr int HOCT = NN * CO / 8;              // 400000 octets in h0
constexpr int CB = (XOCT + HOCT + 255) / 256;  // 1954

__global__ void __launch_bounds__(256) k_deg_cast_prep(
    const int* __restrict__ src, const int* __restrict__ dst, const float* __restrict__ ew,
    float* __restrict__ degp, int* __restrict__ countp, int* __restrict__ rank,
    const float* __restrict__ x, const float* __restrict__ h0,
    __bf16* __restrict__ x_bf, __bf16* __restrict__ h0_bf,
    const float* __restrict__ Wx, const float* __restrict__ Wh,
    const float* __restrict__ bx, const float* __restrict__ bh,
    bf16x8* __restrict__ BfragZR, bf16x8* __restrict__ BfragHT, float* __restrict__ biasC) {
    int b = blockIdx.x;
    if (b < EB) {
        int e = b * 256 + threadIdx.x;
        if (e >= NE) return;
        int s = src[e], d = dst[e];
        float w = (s == d) ? 0.f : ew[e];
        atomicAdd(&degp[(size_t)s * 16], w);
        rank[e] = atomicAdd(&countp[(size_t)d * 16], 1);  // rank doubles as placement slot
    } else if (b < EB + CB) {
        int t = (b - EB) * 256 + threadIdx.x;  // octet index
        const float* sp; __bf16* dp;
        if (t < XOCT) { sp = x + t * 8; dp = x_bf + t * 8; }
        else if (t < XOCT + HOCT) { int u = t - XOCT; sp = h0 + (size_t)u * 8; dp = h0_bf + (size_t)u * 8; }
        else return;
        float4 a = *(const float4*)sp;
        float4 c = *(const float4*)(sp + 4);
        bf16x8 o;
        o[0] = (__bf16)a.x; o[1] = (__bf16)a.y; o[2] = (__bf16)a.z; o[3] = (__bf16)a.w;
        o[4] = (__bf16)c.x; o[5] = (__bf16)c.y; o[6] = (__bf16)c.z; o[7] = (__bf16)c.w;
        *(bf16x8*)dp = o;
    } else {
        int tid = (b - EB - CB) * 256 + threadIdx.x;
        if (tid < 6144) {
            int e = tid, gate, n, kk, l;
            if (e < 4096) {
                int t = e >> 9, rem = e & 511;
                kk = rem >> 6; l = rem & 63;
                n = t * 16 + (l & 15);
                gate = n >> 6;
            } else {
                int e2 = e - 4096;
                int t = e2 >> 9, rem = e2 & 511;
                kk = rem >> 6; l = rem & 63;
                n = t * 16 + (l & 15);
                gate = 2;
            }
            int co = n & 63;
            int k0 = kk * 32 + (l >> 4) * 8;
            bf16x8 f;
#pragma unroll
            for (int j = 0; j < 8; j++) {
                int k = k0 + j;
                float w = 0.f;
                if (k < 48) w = Wx[((gate * 3 + (k >> 4)) * 16 + (k & 15)) * 64 + co];
                else if (k < 240) { int kh = k - 48; w = Wh[((gate * 3 + (kh >> 6)) * 64 + (kh & 63)) * 64 + co]; }
                f[j] = (__bf16)w;
            }
            if (e < 4096) BfragZR[e] = f; else BfragHT[e - 4096] = f;
        } else if (tid < 6144 + 192) {
            int i = tid - 6144;
            biasC[i] = bx[i] + bh[i];
        }
    }
}

// ============================= scan =============================

__global__ void k_scan1(const int* __restrict__ countp, int* __restrict__ S, int* __restrict__ bsums) {
    __shared__ int ts[256];
    int tid = threadIdx.x;
    int base = blockIdx.x * 1024;
    int vals[4]; int s = 0;
#pragma unroll
    for (int j = 0; j < 4; j++) {
        int idx = base + tid * 4 + j;
        int v = (idx < NN) ? countp[(size_t)idx * 16] : 0;
        s += v; vals[j] = s;
    }
    ts[tid] = s;
    __syncthreads();
    for (int off = 1; off < 256; off <<= 1) {
        int v = (tid >= off) ? ts[tid - off] : 0;
        __syncthreads();
        ts[tid] += v;
        __syncthreads();
    }
    int prev = (tid > 0) ? ts[tid - 1] : 0;
#pragma unroll
    for (int j = 0; j < 4; j++) {
        int idx = base + tid * 4 + j;
        if (idx < NN) S[idx] = vals[j] + prev;
    }
    if (tid == 255) bsums[blockIdx.x] = ts[255];
}

__global__ void k_scan2(int* __restrict__ bsums, int nb) {
    if (threadIdx.x == 0 && blockIdx.x == 0) {
        int run = 0;
        for (int i = 0; i < nb; i++) { int v = bsums[i]; bsums[i] = run; run += v; }
    }
}

// rowptr from scan pieces; dinv (compact) = deg > 0 ? rsqrt(deg) : 0
__global__ void k_scan3_dinv(const int* __restrict__ S, const int* __restrict__ bsums,
                             int* __restrict__ rowptr, const float* __restrict__ degp,
                             float* __restrict__ dinv) {
    int i = blockIdx.x * 256 + threadIdx.x;
    if (i >= NN) return;
    int tot = S[i] + bsums[i >> 10];
    rowptr[i + 1] = tot;
    if (i == 0) rowptr[0] = 0;
    float d = degp[(size_t)i * 16];
    dinv[i] = (d > 0.f) ? (1.f / sqrtf(d)) : 0.f;
}

// atomic-free CSR placement; stores w' = dinv[src]*w (the -dinv[dst] factor is
// applied per-node inside the prop kernels)
__global__ void k_place(const int* __restrict__ src, const int* __restrict__ dst,
                        const float* __restrict__ ew, const int* __restrict__ rank,
                        const float* __restrict__ dinv, const int* __restrict__ rowptr,
                        int2* __restrict__ csr_ew) {
    int e = blockIdx.x * 256 + threadIdx.x;
    if (e >= NE) return;
    int s = src[e], d = dst[e];
    float w = (s == d) ? 0.f : ew[e];
    float wp = dinv[s] * w;
    csr_ew[rowptr[d] + rank[e]] = make_int2(s, __float_as_int(wp));
}

// ============================= propagation (bf16, flat layout) =============================
// out[n] = (-dinv[n]*scale) * sum_{e in row n} w'_e * v[src_e]  (- sub[n] if sub)

// C=64: wave per node; 8 edges in flight, 8 lanes x 16B per edge row (128B).
__device__ inline void prop64_body(int n, int lane,
                                   const __bf16* __restrict__ v, const __bf16* __restrict__ sub,
                                   const float* __restrict__ dinv, float scale,
                                   const int* __restrict__ rowptr,
                                   const int2* __restrict__ ew, __bf16* __restrict__ out) {
    int j = lane >> 3, cg = lane & 7;
    int beg = rowptr[n], end = rowptr[n + 1];
    float acc[8] = {0.f, 0.f, 0.f, 0.f, 0.f, 0.f, 0.f, 0.f};
    for (int e = beg + j; e < end; e += 8) {
        int2 p = ew[e];
        float w = __int_as_float(p.y);
        uint4 u = *(const uint4*)((const char*)v + ((size_t)p.x * 128 + cg * 16));
        acc[0] += w * blo(u.x); acc[1] += w * bhi(u.x);
        acc[2] += w * blo(u.y); acc[3] += w * bhi(u.y);
        acc[4] += w * blo(u.z); acc[5] += w * bhi(u.z);
        acc[6] += w * blo(u.w); acc[7] += w * bhi(u.w);
    }
#pragma unroll
    for (int m = 8; m <= 32; m <<= 1) {
#pragma unroll
        for (int i = 0; i < 8; i++) acc[i] += __shfl_xor(acc[i], m, 64);
    }
    if (lane < 8) {
        float f = -dinv[n] * scale;
        float o[8];
        if (sub) {
            uint4 su = *(const uint4*)((const char*)sub + ((size_t)n * 128 + lane * 16));
            o[0] = f * acc[0] - blo(su.x); o[1] = f * acc[1] - bhi(su.x);
            o[2] = f * acc[2] - blo(su.y); o[3] = f * acc[3] - bhi(su.y);
            o[4] = f * acc[4] - blo(su.z); o[5] = f * acc[5] - bhi(su.z);
            o[6] = f * acc[6] - blo(su.w); o[7] = f * acc[7] - bhi(su.w);
        } else {
#pragma unroll
            for (int i = 0; i < 8; i++) o[i] = f * acc[i];
        }
        bf16x8 st;
#pragma unroll
        for (int i = 0; i < 8; i++) st[i] = (__bf16)o[i];
        *(bf16x8*)(out + (size_t)n * 64 + lane * 8) = st;
    }
}

// C=16: wave per node; 32 edges in flight, 2 lanes x 16B per edge row (32B).
__device__ inline void prop16_body(int n, int lane,
                                   const __bf16* __restrict__ v, const __bf16* __restrict__ sub,
                                   const float* __restrict__ dinv, float scale,
                                   const int* __restrict__ rowptr,
                                   const int2* __restrict__ ew, __bf16* __restrict__ out) {
    int j = lane >> 1, cg = lane & 1;
    int beg = rowptr[n], end = rowptr[n + 1];
    float acc[8] = {0.f, 0.f, 0.f, 0.f, 0.f, 0.f, 0.f, 0.f};
    for (int e = beg + j; e < end; e += 32) {
        int2 p = ew[e];
        float w = __int_as_float(p.y);
        uint4 u = *(const uint4*)((const char*)v + ((size_t)p.x * 32 + cg * 16));
        acc[0] += w * blo(u.x); acc[1] += w * bhi(u.x);
        acc[2] += w * blo(u.y); acc[3] += w * bhi(u.y);
        acc[4] += w * blo(u.z); acc[5] += w * bhi(u.z);
        acc[6] += w * blo(u.w); acc[7] += w * bhi(u.w);
    }
#pragma unroll
    for (int m = 2; m <= 32; m <<= 1) {
#pragma unroll
        for (int i = 0; i < 8; i++) acc[i] += __shfl_xor(acc[i], m, 64);
    }
    if (lane < 2) {
        float f = -dinv[n] * scale;
        float o[8];
        if (sub) {
            uint4 su = *(const uint4*)((const char*)sub + ((size_t)n * 32 + lane * 16));
            o[0] = f * acc[0] - blo(su.x); o[1] = f * acc[1] - bhi(su.x);
            o[2] = f * acc[2] - blo(su.y); o[3] = f * acc[3] - bhi(su.y);
            o[4] = f * acc[4] - blo(su.z); o[5] = f * acc[5] - bhi(su.z);
            o[6] = f * acc[6] - blo(su.w); o[7] = f * acc[7] - bhi(su.w);
        } else {
#pragma unroll
            for (int i = 0; i < 8; i++) o[i] = f * acc[i];
        }
        bf16x8 st;
#pragma unroll
        for (int i = 0; i < 8; i++) st[i] = (__bf16)o[i];
        *(bf16x8*)(out + (size_t)n * 16 + lane * 8) = st;
    }
}

// fused stage: waves [0,NN) do h-prop (C=64), waves [NN,2NN) do x-prop (C=16)
__global__ void __launch_bounds__(256) k_stage(
    const __bf16* __restrict__ vh, const __bf16* __restrict__ subh, float sh,
    const __bf16* __restrict__ vx, const __bf16* __restrict__ subx, float sx,
    const float* __restrict__ dinv,
    const int* __restrict__ rowptr, const int2* __restrict__ ew,
    __bf16* __restrict__ outh, __bf16* __restrict__ outx) {
    int gw = blockIdx.x * 4 + (threadIdx.x >> 6);
    int lane = threadIdx.x & 63;
    if (gw < NN) prop64_body(gw, lane, vh, subh, dinv, sh, rowptr, ew, outh);
    else prop16_body(gw - NN, lane, vx, subx, dinv, sx, rowptr, ew, outx);
}

__global__ void __launch_bounds__(256) k_prop64(
    const __bf16* __restrict__ v, const __bf16* __restrict__ sub,
    const float* __restrict__ dinv, float scale,
    const int* __restrict__ rowptr, const int2* __restrict__ ew, __bf16* __restrict__ out) {
    int n = blockIdx.x * 4 + (threadIdx.x >> 6);
    if (n >= NN) return;
    prop64_body(n, threadIdx.x & 63, v, sub, dinv, scale, rowptr, ew, out);
}

// ============================= MFMA dense gates =============================
// Logical A row (K=256): [x(16)|Tx1(16)|Tx2(16)|H(64)|H1(64)|H2(64)|pad(16)], bf16 flat.

__device__ inline bf16x8 load_a_bf(int c, int m,
                                   const __bf16* __restrict__ xb, const __bf16* __restrict__ t1,
                                   const __bf16* __restrict__ t2, const __bf16* __restrict__ hb,
                                   const __bf16* __restrict__ h1, const __bf16* __restrict__ h2) {
    if (c >= 30) {
        bf16x8 a;
#pragma unroll
        for (int j = 0; j < 8; j++) a[j] = (__bf16)0.f;
        return a;
    }
    if (c < 6) {
        const __bf16* base = (c < 2) ? xb : ((c < 4) ? t1 : t2);
        return *(const bf16x8*)(base + (size_t)m * 16 + (c & 1) * 8);
    }
    int d = c - 6;
    const __bf16* base = (d < 8) ? hb : ((d < 16) ? h1 : h2);
    return *(const bf16x8*)(base + (size_t)m * 64 + (d & 7) * 8);
}

// z and r gates: one wave per 16-node tile, 128 output cols (8 out-tiles).
__global__ void __launch_bounds__(256) k_mfma_zr(
    const __bf16* __restrict__ xb, const __bf16* __restrict__ t1, const __bf16* __restrict__ t2,
    const __bf16* __restrict__ hb, const __bf16* __restrict__ h1, const __bf16* __restrict__ h2,
    const bf16x8* __restrict__ Bfrag, const float* __restrict__ biasC,
    const float* __restrict__ h0, __bf16* __restrict__ z_bf, __bf16* __restrict__ hr_bf) {
    int wv = (blockIdx.x * 256 + threadIdx.x) >> 6;
    if (wv >= NN / 16) return;
    int lane = threadIdx.x & 63;
    int q = lane >> 4, r16 = lane & 15;
    int ma = wv * 16 + r16;
    f32x4 acc[8];
#pragma unroll
    for (int t = 0; t < 8; t++) acc[t] = (f32x4){0.f, 0.f, 0.f, 0.f};
#pragma unroll
    for (int kk = 0; kk < 8; kk++) {
        bf16x8 a = load_a_bf(kk * 4 + q, ma, xb, t1, t2, hb, h1, h2);
#pragma unroll
        for (int t = 0; t < 8; t++)
            acc[t] = __builtin_amdgcn_mfma_f32_16x16x32_bf16(a, Bfrag[(t * 8 + kk) * 64 + lane], acc[t], 0, 0, 0);
    }
    int mbase = wv * 16 + q * 4;
#pragma unroll
    for (int t = 0; t < 8; t++) {
        int co = t * 16 + r16;      // 0..127
        float bias = biasC[co];
        int col = co & 63;
#pragma unroll
        for (int reg = 0; reg < 4; reg++) {
            int mm = mbase + reg;
            float p = acc[t][reg] + bias;
            float s = 1.f / (1.f + __expf(-p));
            if (t < 4) z_bf[(size_t)mm * 64 + col] = (__bf16)s;
            else       hr_bf[(size_t)mm * 64 + col] = (__bf16)(s * h0[(size_t)mm * 64 + col]);
        }
    }
}

// htilde gate + GRU combine + fused decoder: wave per 16-node tile.
__global__ void __launch_bounds__(256) k_mfma_ht(
    const __bf16* __restrict__ xb, const __bf16* __restrict__ t1, const __bf16* __restrict__ t2,
    const __bf16* __restrict__ hrb, const __bf16* __restrict__ r1, const __bf16* __restrict__ r2,
    const bf16x8* __restrict__ Bfrag, const float* __restrict__ biasC,
    const __bf16* __restrict__ z_bf, const float* __restrict__ h0,
    const float* __restrict__ Wlin, const float* __restrict__ blin,
    float* __restrict__ hout, float* __restrict__ yout) {
    int wv = (blockIdx.x * 256 + threadIdx.x) >> 6;
    if (wv >= NN / 16) return;
    int lane = threadIdx.x & 63;
    int q = lane >> 4, r16 = lane & 15;
    int ma = wv * 16 + r16;
    f32x4 acc[4];
#pragma unroll
    for (int t = 0; t < 4; t++) acc[t] = (f32x4){0.f, 0.f, 0.f, 0.f};
#pragma unroll
    for (int kk = 0; kk < 8; kk++) {
        bf16x8 a = load_a_bf(kk * 4 + q, ma, xb, t1, t2, hrb, r1, r2);
#pragma unroll
        for (int t = 0; t < 4; t++)
            acc[t] = __builtin_amdgcn_mfma_f32_16x16x32_bf16(a, Bfrag[(t * 8 + kk) * 64 + lane], acc[t], 0, 0, 0);
    }
    int mbase = wv * 16 + q * 4;
    float hbuf[4][4];
#pragma unroll
    for (int t = 0; t < 4; t++) {
        int co = t * 16 + r16;   // 0..63
        float bias = biasC[128 + co];
#pragma unroll
        for (int reg = 0; reg < 4; reg++) {
            int mm = mbase + reg;
            float p = acc[t][reg] + bias;
            float htl = tanhf(p);
            float zv = (float)z_bf[(size_t)mm * 64 + co];
            float h0v = h0[(size_t)mm * 64 + co];
            float hn = zv * h0v + (1.f - zv) * htl;
            hout[(size_t)mm * 64 + co] = hn;
            hbuf[t][reg] = hn;
        }
    }
    // fused y = relu(h) @ Wlin + blin : partials per lane, reduce over the 16-lane group
    float ya[4][DD];
#pragma unroll
    for (int reg = 0; reg < 4; reg++)
#pragma unroll
        for (int d = 0; d < DD; d++) ya[reg][d] = 0.f;
#pragma unroll
    for (int t = 0; t < 4; t++) {
        int cb = (t * 16 + r16) * DD;
        float wl[DD];
#pragma unroll
        for (int d = 0; d < DD; d++) wl[d] = Wlin[cb + d];
#pragma unroll
        for (int reg = 0; reg < 4; reg++) {
            float rh = fmaxf(hbuf[t][reg], 0.f);
#pragma unroll
            for (int d = 0; d < DD; d++) ya[reg][d] += rh * wl[d];
        }
    }
#pragma unroll
    for (int m = 1; m <= 8; m <<= 1) {
#pragma unroll
        for (int reg = 0; reg < 4; reg++)
#pragma unroll
            for (int d = 0; d < DD; d++) ya[reg][d] += __shfl_xor(ya[reg][d], m, 64);
    }
    if (r16 < DD) {
        float b = blin[r16];
#pragma unroll
        for (int reg = 0; reg < 4; reg++) {
            float v = (r16 == 0) ? ya[reg][0] : (r16 == 1) ? ya[reg][1] : (r16 == 2) ? ya[reg][2]
                    : (r16 == 3) ? ya[reg][3] : (r16 == 4) ? ya[reg][4] : (r16 == 5) ? ya[reg][5]
                    : ya[reg][6];
            yout[(size_t)(mbase + reg) * DD + r16] = v + b;
        }
    }
}

// ============================= launch =============================

extern "C" void kernel_launch(void* const* d_in, const int* in_sizes, int n_in,
                              void* d_out, int out_size, void* d_ws, size_t ws_size,
                              hipStream_t stream) {
    (void)in_sizes; (void)n_in; (void)out_size; (void)ws_size;
    const float* x    = (const float*)d_in[0];
    const int*   eidx = (const int*)d_in[1];
    const float* ew   = (const float*)d_in[2];
    const float* h0   = (const float*)d_in[3];
    const float* Wx   = (const float*)d_in[4];
    const float* Wh   = (const float*)d_in[5];
    const float* bx   = (const float*)d_in[6];
    const float* bh   = (const float*)d_in[7];
    const float* Wlin = (const float*)d_in[8];
    const float* blin = (const float*)d_in[9];
    const int* src = eidx;
    const int* dst = eidx + NE;

    char* ws = (char*)d_ws;
    size_t off = 0;
    auto alloc = [&](size_t nbytes) -> void* {
        void* p = ws + off;
        off += (nbytes + 255) & ~(size_t)255;
        return p;
    };
    float*  degp    = (float*)alloc((size_t)NN * 16 * 4);  // padded: 1 counter / 64B line
    int*    countp  = (int*)alloc((size_t)NN * 16 * 4);    // padded
    float*  dinv    = (float*)alloc(NN * 4);               // compact
    int*    S       = (int*)alloc(NN * 4);
    int*    rowptr  = (int*)alloc((NN + 1) * 4);
    int*    bsums   = (int*)alloc(64 * 4);
    int*    rank    = (int*)alloc((size_t)NE * 4);
    int2*   csr_ew  = (int2*)alloc((size_t)NE * 8);
    __bf16* x_bf    = (__bf16*)alloc((size_t)NN * CI * 2);
    __bf16* h0_bf   = (__bf16*)alloc((size_t)NN * CO * 2);
    __bf16* Tx1     = (__bf16*)alloc((size_t)NN * CI * 2);
    __bf16* Tx2     = (__bf16*)alloc((size_t)NN * CI * 2);
    __bf16* Th1     = (__bf16*)alloc((size_t)NN * CO * 2);
    __bf16* Th2     = (__bf16*)alloc((size_t)NN * CO * 2);
    __bf16* hr_bf   = (__bf16*)alloc((size_t)NN * CO * 2);
    __bf16* z_bf    = (__bf16*)alloc((size_t)NN * CO * 2);
    bf16x8* BfragZR = (bf16x8*)alloc(4096 * 16);
    bf16x8* BfragHT = (bf16x8*)alloc(2048 * 16);
    float*  biasC   = (float*)alloc(192 * 4);

    float* hout = (float*)d_out;
    float* yout = hout + (size_t)NN * CO;

    constexpr int NB = (NN + 1023) / 1024;   // scan chunks
    const int NBLK = (NN + 255) / 256;
    const int PROPB = (NN + 3) / 4;          // 4 waves/block, wave per node
    const int STAGEB = (2 * NN + 3) / 4;     // fused h+x stage
    const int GEMMB = (NN / 16 * 64 + 255) / 256;

    hipMemsetAsync(degp, 0, (size_t)NN * 16 * 4, stream);
    hipMemsetAsync(countp, 0, (size_t)NN * 16 * 4, stream);

    k_deg_cast_prep<<<EB + CB + 25, 256, 0, stream>>>(
        src, dst, ew, degp, countp, rank, x, h0, x_bf, h0_bf,
        Wx, Wh, bx, bh, BfragZR, BfragHT, biasC);
    k_scan1<<<NB, 256, 0, stream>>>(countp, S, bsums);
    k_scan2<<<1, 64, 0, stream>>>(bsums, NB);
    k_scan3_dinv<<<NBLK, 256, 0, stream>>>(S, bsums, rowptr, degp, dinv);
    k_place<<<EB, 256, 0, stream>>>(src, dst, ew, rank, dinv, rowptr, csr_ew);

    // stage 1: Th1 = P(h0), Tx1 = P(x)
    k_stage<<<STAGEB, 256, 0, stream>>>(h0_bf, nullptr, 1.f, x_bf, nullptr, 1.f,
                                        dinv, rowptr, csr_ew, Th1, Tx1);
    // stage 2: Th2 = 2P(Th1) - h0, Tx2 = 2P(Tx1) - x
    k_stage<<<STAGEB, 256, 0, stream>>>(Th1, h0_bf, 2.f, Tx1, x_bf, 2.f,
                                        dinv, rowptr, csr_ew, Th2, Tx2);

    // z and r gates (r fused into hr = r*h0)
    k_mfma_zr<<<GEMMB, 256, 0, stream>>>(x_bf, Tx1, Tx2, h0_bf, Th1, Th2,
                                         BfragZR, biasC, h0, z_bf, hr_bf);
    // propagate hr (reuse Th1/Th2 as Thr1/Thr2)
    k_prop64<<<PROPB, 256, 0, stream>>>(hr_bf, nullptr, dinv, 1.f, rowptr, csr_ew, Th1);
    k_prop64<<<PROPB, 256, 0, stream>>>(Th1, hr_bf, dinv, 2.f, rowptr, csr_ew, Th2);
    // htilde gate + GRU combine + fused decoder -> h, y
    k_mfma_ht<<<GEMMB, 256, 0, stream>>>(x_bf, Tx1, Tx2, hr_bf, Th1, Th2,
                                         BfragHT, biasC, z_bf, h0, Wlin, blin, hout, yout);
}

// Round 7
// 372.655 us; speedup vs baseline: 1.2224x; 1.0032x over previous
//
#include <hip/hip_runtime.h>

// Problem constants (from reference)
constexpr int NN = 50000;   // nodes
constexpr int NE = 800000;  // edges
constexpr int CI = 16;      // in channels
constexpr int CO = 64;      // out channels
constexpr int DD = 7;       // decoder dim

typedef __bf16 bf16x8 __attribute__((ext_vector_type(8)));
typedef float  f32x4  __attribute__((ext_vector_type(4)));
typedef float  f32x2  __attribute__((ext_vector_type(2)));

__device__ inline float blo(unsigned u) { return __uint_as_float(u << 16); }
__device__ inline float bhi(unsigned u) { return __uint_as_float(u & 0xffff0000u); }

// fp8 e4m3 helpers (HW packed converts; OCP format on gfx950)
__device__ inline void acc8_fp8(float acc[8], float w, uint2 u) {
    f32x2 c;
    c = __builtin_amdgcn_cvt_pk_f32_fp8(u.x, false); acc[0] += w * c[0]; acc[1] += w * c[1];
    c = __builtin_amdgcn_cvt_pk_f32_fp8(u.x, true);  acc[2] += w * c[0]; acc[3] += w * c[1];
    c = __builtin_amdgcn_cvt_pk_f32_fp8(u.y, false); acc[4] += w * c[0]; acc[5] += w * c[1];
    c = __builtin_amdgcn_cvt_pk_f32_fp8(u.y, true);  acc[6] += w * c[0]; acc[7] += w * c[1];
}
__device__ inline uint2 pack_fp8x8(const float o[8]) {
    int t0 = __builtin_amdgcn_cvt_pk_fp8_f32(o[0], o[1], 0, false);
    t0 = __builtin_amdgcn_cvt_pk_fp8_f32(o[2], o[3], t0, true);
    int t1 = __builtin_amdgcn_cvt_pk_fp8_f32(o[4], o[5], 0, false);
    t1 = __builtin_amdgcn_cvt_pk_fp8_f32(o[6], o[7], t1, true);
    uint2 r; r.x = (unsigned)t0; r.y = (unsigned)t1; return r;
}
__device__ inline unsigned char fp8_of(float v) {
    return (unsigned char)(__builtin_amdgcn_cvt_pk_fp8_f32(v, v, 0, false) & 0xff);
}

// ================= fused: edge histograms(+rank) + casts + B-prep =================

constexpr int EB = (NE + 255) / 256;           // 3125
constexpr int XOCT = NN * CI / 8;              // 100000 octets in x
constexpr int HOCT = NN * CO / 8;              // 400000 octets in h0
constexpr int CB = (XOCT + HOCT + 255) / 256;  // 1954

__global__ void __launch_bounds__(256) k_deg_cast_prep(
    const int* __restrict__ src, const int* __restrict__ dst, const float* __restrict__ ew,
    float* __restrict__ deg, int* __restrict__ count, int* __restrict__ rank,
    const float* __restrict__ x, const float* __restrict__ h0,
    __bf16* __restrict__ x_bf, __bf16* __restrict__ h0_bf, unsigned char* __restrict__ h0_f8,
    const float* __restrict__ Wx, const float* __restrict__ Wh,
    const float* __restrict__ bx, const float* __restrict__ bh,
    bf16x8* __restrict__ BfragZR, bf16x8* __restrict__ BfragHT, float* __restrict__ biasC) {
    int b = blockIdx.x;
    if (b < EB) {
        int e = b * 256 + threadIdx.x;
        if (e >= NE) return;
        int s = src[e], d = dst[e];
        float w = (s == d) ? 0.f : ew[e];
        atomicAdd(&deg[s], w);
        rank[e] = atomicAdd(&count[d], 1);   // rank doubles as placement slot
    } else if (b < EB + CB) {
        int t = (b - EB) * 256 + threadIdx.x;  // octet index
        if (t < XOCT) {
            const float* sp = x + (size_t)t * 8;
            float4 a = *(const float4*)sp;
            float4 c = *(const float4*)(sp + 4);
            bf16x8 o;
            o[0] = (__bf16)a.x; o[1] = (__bf16)a.y; o[2] = (__bf16)a.z; o[3] = (__bf16)a.w;
            o[4] = (__bf16)c.x; o[5] = (__bf16)c.y; o[6] = (__bf16)c.z; o[7] = (__bf16)c.w;
            *(bf16x8*)(x_bf + (size_t)t * 8) = o;
        } else if (t < XOCT + HOCT) {
            int u = t - XOCT;
            const float* sp = h0 + (size_t)u * 8;
            float4 a = *(const float4*)sp;
            float4 c = *(const float4*)(sp + 4);
            bf16x8 o;
            o[0] = (__bf16)a.x; o[1] = (__bf16)a.y; o[2] = (__bf16)a.z; o[3] = (__bf16)a.w;
            o[4] = (__bf16)c.x; o[5] = (__bf16)c.y; o[6] = (__bf16)c.z; o[7] = (__bf16)c.w;
            *(bf16x8*)(h0_bf + (size_t)u * 8) = o;
            float f[8] = {a.x, a.y, a.z, a.w, c.x, c.y, c.z, c.w};
            *(uint2*)(h0_f8 + (size_t)u * 8) = pack_fp8x8(f);
        }
    } else {
        int tid = (b - EB - CB) * 256 + threadIdx.x;
        if (tid < 6144) {
            int e = tid, gate, n, kk, l;
            if (e < 4096) {
                int t = e >> 9, rem = e & 511;
                kk = rem >> 6; l = rem & 63;
                n = t * 16 + (l & 15);
                gate = n >> 6;
            } else {
                int e2 = e - 4096;
                int t = e2 >> 9, rem = e2 & 511;
                kk = rem >> 6; l = rem & 63;
                n = t * 16 + (l & 15);
                gate = 2;
            }
            int co = n & 63;
            int k0 = kk * 32 + (l >> 4) * 8;
            bf16x8 f;
#pragma unroll
            for (int j = 0; j < 8; j++) {
                int k = k0 + j;
                float w = 0.f;
                if (k < 48) w = Wx[((gate * 3 + (k >> 4)) * 16 + (k & 15)) * 64 + co];
                else if (k < 240) { int kh = k - 48; w = Wh[((gate * 3 + (kh >> 6)) * 64 + (kh & 63)) * 64 + co]; }
                f[j] = (__bf16)w;
            }
            if (e < 4096) BfragZR[e] = f; else BfragHT[e - 4096] = f;
        } else if (tid < 6144 + 192) {
            int i = tid - 6144;
            biasC[i] = bx[i] + bh[i];
        }
    }
}

// ============================= scan =============================

__global__ void k_scan1(const int* __restrict__ count, int* __restrict__ S, int* __restrict__ bsums) {
    __shared__ int ts[256];
    int tid = threadIdx.x;
    int base = blockIdx.x * 1024;
    int vals[4]; int s = 0;
#pragma unroll
    for (int j = 0; j < 4; j++) {
        int idx = base + tid * 4 + j;
        int v = (idx < NN) ? count[idx] : 0;
        s += v; vals[j] = s;
    }
    ts[tid] = s;
    __syncthreads();
    for (int off = 1; off < 256; off <<= 1) {
        int v = (tid >= off) ? ts[tid - off] : 0;
        __syncthreads();
        ts[tid] += v;
        __syncthreads();
    }
    int prev = (tid > 0) ? ts[tid - 1] : 0;
#pragma unroll
    for (int j = 0; j < 4; j++) {
        int idx = base + tid * 4 + j;
        if (idx < NN) S[idx] = vals[j] + prev;
    }
    if (tid == 255) bsums[blockIdx.x] = ts[255];
}

__global__ void k_scan2(int* __restrict__ bsums, int nb) {
    if (threadIdx.x == 0 && blockIdx.x == 0) {
        int run = 0;
        for (int i = 0; i < nb; i++) { int v = bsums[i]; bsums[i] = run; run += v; }
    }
}

__global__ void k_scan3_dinv(const int* __restrict__ S, const int* __restrict__ bsums,
                             int* __restrict__ rowptr, float* __restrict__ deg) {
    int i = blockIdx.x * 256 + threadIdx.x;
    if (i >= NN) return;
    int tot = S[i] + bsums[i >> 10];
    rowptr[i + 1] = tot;
    if (i == 0) rowptr[0] = 0;
    float d = deg[i];
    deg[i] = (d > 0.f) ? (1.f / sqrtf(d)) : 0.f;
}

// atomic-free placement; meta = u16 src | bf16(dinv[src]*w) in high 16 bits (4B/edge)
__global__ void k_place(const int* __restrict__ src, const int* __restrict__ dst,
                        const float* __restrict__ ew, const int* __restrict__ rank,
                        const float* __restrict__ dinv, const int* __restrict__ rowptr,
                        unsigned* __restrict__ csr_ew) {
    int e = blockIdx.x * 256 + threadIdx.x;
    if (e >= NE) return;
    int s = src[e], d = dst[e];
    float w = (s == d) ? 0.f : ew[e];
    float wp = dinv[s] * w;
    __bf16 wb = (__bf16)wp;
    unsigned short ub = __builtin_bit_cast(unsigned short, wb);
    csr_ew[rowptr[d] + rank[e]] = (unsigned)s | ((unsigned)ub << 16);
}

// ============================= propagation =============================
// out[n] = (-dinv[n]*scale) * sum_{e in row n} w'_e * v[src_e]  (- sub[n] if sub)

// C=64, fp8 gather: wave per node; 8 edges in flight, 8 lanes x 8B = 64B row (1 line/edge).
__device__ inline void prop64_body(int n, int lane,
                                   const unsigned char* __restrict__ v8,
                                   const __bf16* __restrict__ sub,
                                   const float* __restrict__ dinv, float scale,
                                   const int* __restrict__ rowptr,
                                   const unsigned* __restrict__ ew,
                                   __bf16* __restrict__ out_bf,
                                   unsigned char* __restrict__ out_f8) {
    int j = lane >> 3, cg = lane & 7;
    int beg = rowptr[n], end = rowptr[n + 1];
    float acc[8] = {0.f, 0.f, 0.f, 0.f, 0.f, 0.f, 0.f, 0.f};
    for (int e = beg + j; e < end; e += 8) {
        unsigned p = ew[e];
        float w = bhi(p);
        int s = p & 0xffff;
        uint2 u = *(const uint2*)(v8 + (size_t)s * 64 + cg * 8);
        acc8_fp8(acc, w, u);
    }
#pragma unroll
    for (int m = 8; m <= 32; m <<= 1) {
#pragma unroll
        for (int i = 0; i < 8; i++) acc[i] += __shfl_xor(acc[i], m, 64);
    }
    if (lane < 8) {
        float f = -dinv[n] * scale;
        float o[8];
        if (sub) {
            uint4 su = *(const uint4*)((const char*)sub + ((size_t)n * 128 + lane * 16));
            o[0] = f * acc[0] - blo(su.x); o[1] = f * acc[1] - bhi(su.x);
            o[2] = f * acc[2] - blo(su.y); o[3] = f * acc[3] - bhi(su.y);
            o[4] = f * acc[4] - blo(su.z); o[5] = f * acc[5] - bhi(su.z);
            o[6] = f * acc[6] - blo(su.w); o[7] = f * acc[7] - bhi(su.w);
        } else {
#pragma unroll
            for (int i = 0; i < 8; i++) o[i] = f * acc[i];
        }
        bf16x8 st;
#pragma unroll
        for (int i = 0; i < 8; i++) st[i] = (__bf16)o[i];
        *(bf16x8*)(out_bf + (size_t)n * 64 + lane * 8) = st;
        if (out_f8) *(uint2*)(out_f8 + (size_t)n * 64 + lane * 8) = pack_fp8x8(o);
    }
}

// C=16 bf16 gather (32B rows, already 1 line/edge): 32 edges in flight.
__device__ inline void prop16_body(int n, int lane,
                                   const __bf16* __restrict__ v, const __bf16* __restrict__ sub,
                                   const float* __restrict__ dinv, float scale,
                                   const int* __restrict__ rowptr,
                                   const unsigned* __restrict__ ew, __bf16* __restrict__ out) {
    int j = lane >> 1, cg = lane & 1;
    int beg = rowptr[n], end = rowptr[n + 1];
    float acc[8] = {0.f, 0.f, 0.f, 0.f, 0.f, 0.f, 0.f, 0.f};
    for (int e = beg + j; e < end; e += 32) {
        unsigned p = ew[e];
        float w = bhi(p);
        int s = p & 0xffff;
        uint4 u = *(const uint4*)((const char*)v + ((size_t)s * 32 + cg * 16));
        acc[0] += w * blo(u.x); acc[1] += w * bhi(u.x);
        acc[2] += w * blo(u.y); acc[3] += w * bhi(u.y);
        acc[4] += w * blo(u.z); acc[5] += w * bhi(u.z);
        acc[6] += w * blo(u.w); acc[7] += w * bhi(u.w);
    }
#pragma unroll
    for (int m = 2; m <= 32; m <<= 1) {
#pragma unroll
        for (int i = 0; i < 8; i++) acc[i] += __shfl_xor(acc[i], m, 64);
    }
    if (lane < 2) {
        float f = -dinv[n] * scale;
        float o[8];
        if (sub) {
            uint4 su = *(const uint4*)((const char*)sub + ((size_t)n * 32 + lane * 16));
            o[0] = f * acc[0] - blo(su.x); o[1] = f * acc[1] - bhi(su.x);
            o[2] = f * acc[2] - blo(su.y); o[3] = f * acc[3] - bhi(su.y);
            o[4] = f * acc[4] - blo(su.z); o[5] = f * acc[5] - bhi(su.z);
            o[6] = f * acc[6] - blo(su.w); o[7] = f * acc[7] - bhi(su.w);
        } else {
#pragma unroll
            for (int i = 0; i < 8; i++) o[i] = f * acc[i];
        }
        bf16x8 st;
#pragma unroll
        for (int i = 0; i < 8; i++) st[i] = (__bf16)o[i];
        *(bf16x8*)(out + (size_t)n * 16 + lane * 8) = st;
    }
}

// fused stage: waves [0,NN) do h-prop (C=64 fp8), waves [NN,2NN) do x-prop (C=16 bf16)
__global__ void __launch_bounds__(256) k_stage(
    const unsigned char* __restrict__ vh8, const __bf16* __restrict__ subh, float sh,
    const __bf16* __restrict__ vx, const __bf16* __restrict__ subx, float sx,
    const float* __restrict__ dinv,
    const int* __restrict__ rowptr, const unsigned* __restrict__ ew,
    __bf16* __restrict__ outh_bf, unsigned char* __restrict__ outh_f8,
    __bf16* __restrict__ outx) {
    int gw = blockIdx.x * 4 + (threadIdx.x >> 6);
    int lane = threadIdx.x & 63;
    if (gw < NN) prop64_body(gw, lane, vh8, subh, dinv, sh, rowptr, ew, outh_bf, outh_f8);
    else prop16_body(gw - NN, lane, vx, subx, dinv, sx, rowptr, ew, outx);
}

__global__ void __launch_bounds__(256) k_prop64(
    const unsigned char* __restrict__ v8, const __bf16* __restrict__ sub,
    const float* __restrict__ dinv, float scale,
    const int* __restrict__ rowptr, const unsigned* __restrict__ ew,
    __bf16* __restrict__ out_bf, unsigned char* __restrict__ out_f8) {
    int n = blockIdx.x * 4 + (threadIdx.x >> 6);
    if (n >= NN) return;
    prop64_body(n, threadIdx.x & 63, v8, sub, dinv, scale, rowptr, ew, out_bf, out_f8);
}

// ============================= MFMA dense gates =============================
// Logical A row (K=256): [x(16)|Tx1(16)|Tx2(16)|H(64)|H1(64)|H2(64)|pad(16)], bf16 flat.

__device__ inline bf16x8 load_a_bf(int c, int m,
                                   const __bf16* __restrict__ xb, const __bf16* __restrict__ t1,
                                   const __bf16* __restrict__ t2, const __bf16* __restrict__ hb,
                                   const __bf16* __restrict__ h1, const __bf16* __restrict__ h2) {
    if (c >= 30) {
        bf16x8 a;
#pragma unroll
        for (int j = 0; j < 8; j++) a[j] = (__bf16)0.f;
        return a;
    }
    if (c < 6) {
        const __bf16* base = (c < 2) ? xb : ((c < 4) ? t1 : t2);
        return *(const bf16x8*)(base + (size_t)m * 16 + (c & 1) * 8);
    }
    int d = c - 6;
    const __bf16* base = (d < 8) ? hb : ((d < 16) ? h1 : h2);
    return *(const bf16x8*)(base + (size_t)m * 64 + (d & 7) * 8);
}

// z and r gates: one wave per 16-node tile, 128 output cols (8 out-tiles).
__global__ void __launch_bounds__(256) k_mfma_zr(
    const __bf16* __restrict__ xb, const __bf16* __restrict__ t1, const __bf16* __restrict__ t2,
    const __bf16* __restrict__ hb, const __bf16* __restrict__ h1, const __bf16* __restrict__ h2,
    const bf16x8* __restrict__ Bfrag, const float* __restrict__ biasC,
    const float* __restrict__ h0, __bf16* __restrict__ z_bf,
    __bf16* __restrict__ hr_bf, unsigned char* __restrict__ hr_f8) {
    int wv = (blockIdx.x * 256 + threadIdx.x) >> 6;
    if (wv >= NN / 16) return;
    int lane = threadIdx.x & 63;
    int q = lane >> 4, r16 = lane & 15;
    int ma = wv * 16 + r16;
    f32x4 acc[8];
#pragma unroll
    for (int t = 0; t < 8; t++) acc[t] = (f32x4){0.f, 0.f, 0.f, 0.f};
#pragma unroll
    for (int kk = 0; kk < 8; kk++) {
        bf16x8 a = load_a_bf(kk * 4 + q, ma, xb, t1, t2, hb, h1, h2);
#pragma unroll
        for (int t = 0; t < 8; t++)
            acc[t] = __builtin_amdgcn_mfma_f32_16x16x32_bf16(a, Bfrag[(t * 8 + kk) * 64 + lane], acc[t], 0, 0, 0);
    }
    int mbase = wv * 16 + q * 4;
#pragma unroll
    for (int t = 0; t < 8; t++) {
        int co = t * 16 + r16;      // 0..127
        float bias = biasC[co];
        int col = co & 63;
#pragma unroll
        for (int reg = 0; reg < 4; reg++) {
            int mm = mbase + reg;
            float p = acc[t][reg] + bias;
            float s = 1.f / (1.f + __expf(-p));
            if (t < 4) z_bf[(size_t)mm * 64 + col] = (__bf16)s;
            else {
                float hrv = s * h0[(size_t)mm * 64 + col];
                hr_bf[(size_t)mm * 64 + col] = (__bf16)hrv;
                hr_f8[(size_t)mm * 64 + col] = fp8_of(hrv);
            }
        }
    }
}

// htilde gate + GRU combine + fused decoder: wave per 16-node tile.
__global__ void __launch_bounds__(256) k_mfma_ht(
    const __bf16* __restrict__ xb, const __bf16* __restrict__ t1, const __bf16* __restrict__ t2,
    const __bf16* __restrict__ hrb, const __bf16* __restrict__ r1, const __bf16* __restrict__ r2,
    const bf16x8* __restrict__ Bfrag, const float* __restrict__ biasC,
    const __bf16* __restrict__ z_bf, const float* __restrict__ h0,
    const float* __restrict__ Wlin, const float* __restrict__ blin,
    float* __restrict__ hout, float* __restrict__ yout) {
    int wv = (blockIdx.x * 256 + threadIdx.x) >> 6;
    if (wv >= NN / 16) return;
    int lane = threadIdx.x & 63;
    int q = lane >> 4, r16 = lane & 15;
    int ma = wv * 16 + r16;
    f32x4 acc[4];
#pragma unroll
    for (int t = 0; t < 4; t++) acc[t] = (f32x4){0.f, 0.f, 0.f, 0.f};
#pragma unroll
    for (int kk = 0; kk < 8; kk++) {
        bf16x8 a = load_a_bf(kk * 4 + q, ma, xb, t1, t2, hrb, r1, r2);
#pragma unroll
        for (int t = 0; t < 4; t++)
            acc[t] = __builtin_amdgcn_mfma_f32_16x16x32_bf16(a, Bfrag[(t * 8 + kk) * 64 + lane], acc[t], 0, 0, 0);
    }
    int mbase = wv * 16 + q * 4;
    float hbuf[4][4];
#pragma unroll
    for (int t = 0; t < 4; t++) {
        int co = t * 16 + r16;   // 0..63
        float bias = biasC[128 + co];
#pragma unroll
        for (int reg = 0; reg < 4; reg++) {
            int mm = mbase + reg;
            float p = acc[t][reg] + bias;
            float htl = tanhf(p);
            float zv = (float)z_bf[(size_t)mm * 64 + co];
            float h0v = h0[(size_t)mm * 64 + co];
            float hn = zv * h0v + (1.f - zv) * htl;
            hout[(size_t)mm * 64 + co] = hn;
            hbuf[t][reg] = hn;
        }
    }
    // fused y = relu(h) @ Wlin + blin : partials per lane, reduce over the 16-lane group
    float ya[4][DD];
#pragma unroll
    for (int reg = 0; reg < 4; reg++)
#pragma unroll
        for (int d = 0; d < DD; d++) ya[reg][d] = 0.f;
#pragma unroll
    for (int t = 0; t < 4; t++) {
        int cb = (t * 16 + r16) * DD;
        float wl[DD];
#pragma unroll
        for (int d = 0; d < DD; d++) wl[d] = Wlin[cb + d];
#pragma unroll
        for (int reg = 0; reg < 4; reg++) {
            float rh = fmaxf(hbuf[t][reg], 0.f);
#pragma unroll
            for (int d = 0; d < DD; d++) ya[reg][d] += rh * wl[d];
        }
    }
#pragma unroll
    for (int m = 1; m <= 8; m <<= 1) {
#pragma unroll
        for (int reg = 0; reg < 4; reg++)
#pragma unroll
            for (int d = 0; d < DD; d++) ya[reg][d] += __shfl_xor(ya[reg][d], m, 64);
    }
    if (r16 < DD) {
        float b = blin[r16];
#pragma unroll
        for (int reg = 0; reg < 4; reg++) {
            float v = (r16 == 0) ? ya[reg][0] : (r16 == 1) ? ya[reg][1] : (r16 == 2) ? ya[reg][2]
                    : (r16 == 3) ? ya[reg][3] : (r16 == 4) ? ya[reg][4] : (r16 == 5) ? ya[reg][5]
                    : ya[reg][6];
            yout[(size_t)(mbase + reg) * DD + r16] = v + b;
        }
    }
}

// ============================= launch =============================

extern "C" void kernel_launch(void* const* d_in, const int* in_sizes, int n_in,
                              void* d_out, int out_size, void* d_ws, size_t ws_size,
                              hipStream_t stream) {
    (void)in_sizes; (void)n_in; (void)out_size; (void)ws_size;
    const float* x    = (const float*)d_in[0];
    const int*   eidx = (const int*)d_in[1];
    const float* ew   = (const float*)d_in[2];
    const float* h0   = (const float*)d_in[3];
    const float* Wx   = (const float*)d_in[4];
    const float* Wh   = (const float*)d_in[5];
    const float* bx   = (const float*)d_in[6];
    const float* bh   = (const float*)d_in[7];
    const float* Wlin = (const float*)d_in[8];
    const float* blin = (const float*)d_in[9];
    const int* src = eidx;
    const int* dst = eidx + NE;

    char* ws = (char*)d_ws;
    size_t off = 0;
    auto alloc = [&](size_t nbytes) -> void* {
        void* p = ws + off;
        off += (nbytes + 255) & ~(size_t)255;
        return p;
    };
    float*  dinv    = (float*)alloc(NN * 4);        // deg, then dinv in-place
    int*    count   = (int*)alloc(NN * 4);
    int*    S       = (int*)alloc(NN * 4);
    int*    rowptr  = (int*)alloc((NN + 1) * 4);
    int*    bsums   = (int*)alloc(64 * 4);
    int*    rank    = (int*)alloc((size_t)NE * 4);
    unsigned* csr_ew = (unsigned*)alloc((size_t)NE * 4);
    __bf16* x_bf    = (__bf16*)alloc((size_t)NN * CI * 2);
    __bf16* h0_bf   = (__bf16*)alloc((size_t)NN * CO * 2);
    unsigned char* h0_f8 = (unsigned char*)alloc((size_t)NN * CO);
    unsigned char* T1_f8 = (unsigned char*)alloc((size_t)NN * CO);  // Th1_f8 / Thr1_f8
    unsigned char* hr_f8 = (unsigned char*)alloc((size_t)NN * CO);
    __bf16* Tx1     = (__bf16*)alloc((size_t)NN * CI * 2);
    __bf16* Tx2     = (__bf16*)alloc((size_t)NN * CI * 2);
    __bf16* Th1     = (__bf16*)alloc((size_t)NN * CO * 2);
    __bf16* Th2     = (__bf16*)alloc((size_t)NN * CO * 2);
    __bf16* hr_bf   = (__bf16*)alloc((size_t)NN * CO * 2);
    __bf16* z_bf    = (__bf16*)alloc((size_t)NN * CO * 2);
    bf16x8* BfragZR = (bf16x8*)alloc(4096 * 16);
    bf16x8* BfragHT = (bf16x8*)alloc(2048 * 16);
    float*  biasC   = (float*)alloc(192 * 4);

    float* hout = (float*)d_out;
    float* yout = hout + (size_t)NN * CO;

    constexpr int NB = (NN + 1023) / 1024;   // scan chunks
    const int NBLK = (NN + 255) / 256;
    const int PROPB = (NN + 3) / 4;          // 4 waves/block, wave per node
    const int STAGEB = (2 * NN + 3) / 4;     // fused h+x stage
    const int GEMMB = (NN / 16 * 64 + 255) / 256;

    hipMemsetAsync(dinv, 0, NN * 4, stream);
    hipMemsetAsync(count, 0, NN * 4, stream);

    k_deg_cast_prep<<<EB + CB + 25, 256, 0, stream>>>(
        src, dst, ew, dinv, count, rank, x, h0, x_bf, h0_bf, h0_f8,
        Wx, Wh, bx, bh, BfragZR, BfragHT, biasC);
    k_scan1<<<NB, 256, 0, stream>>>(count, S, bsums);
    k_scan2<<<1, 64, 0, stream>>>(bsums, NB);
    k_scan3_dinv<<<NBLK, 256, 0, stream>>>(S, bsums, rowptr, dinv);
    k_place<<<EB, 256, 0, stream>>>(src, dst, ew, rank, dinv, rowptr, csr_ew);

    // stage 1: Th1 = P(h0) (bf16 + fp8 copy), Tx1 = P(x)
    k_stage<<<STAGEB, 256, 0, stream>>>(h0_f8, nullptr, 1.f, x_bf, nullptr, 1.f,
                                        dinv, rowptr, csr_ew, Th1, T1_f8, Tx1);
    // stage 2: Th2 = 2P(Th1) - h0, Tx2 = 2P(Tx1) - x
    k_stage<<<STAGEB, 256, 0, stream>>>(T1_f8, h0_bf, 2.f, Tx1, x_bf, 2.f,
                                        dinv, rowptr, csr_ew, Th2, nullptr, Tx2);

    // z and r gates (r fused into hr = r*h0, bf16 + fp8 copy)
    k_mfma_zr<<<GEMMB, 256, 0, stream>>>(x_bf, Tx1, Tx2, h0_bf, Th1, Th2,
                                         BfragZR, biasC, h0, z_bf, hr_bf, hr_f8);
    // propagate hr (reuse Th1/Th2 as Thr1/Thr2, T1_f8 as Thr1_f8)
    k_prop64<<<PROPB, 256, 0, stream>>>(hr_f8, nullptr, dinv, 1.f, rowptr, csr_ew, Th1, T1_f8);
    k_prop64<<<PROPB, 256, 0, stream>>>(T1_f8, hr_bf, dinv, 2.f, rowptr, csr_ew, Th2, nullptr);
    // htilde gate + GRU combine + fused decoder -> h, y
    k_mfma_ht<<<GEMMB, 256, 0, stream>>>(x_bf, Tx1, Tx2, hr_bf, Th1, Th2,
                                         BfragHT, biasC, z_bf, h0, Wlin, blin, hout, yout);
}

// Round 9
// 363.632 us; speedup vs baseline: 1.2527x; 1.0248x over previous
//
#include <hip/hip_runtime.h>

// Problem constants (from reference)
constexpr int NN = 50000;   // nodes
constexpr int NE = 800000;  // edges
constexpr int CI = 16;      // in channels
constexpr int CO = 64;      // out channels
constexpr int DD = 7;       // decoder dim

typedef __bf16 bf16x8 __attribute__((ext_vector_type(8)));
typedef float  f32x4  __attribute__((ext_vector_type(4)));
typedef float  f32x2  __attribute__((ext_vector_type(2)));

__device__ inline float blo(unsigned u) { return __uint_as_float(u << 16); }
__device__ inline float bhi(unsigned u) { return __uint_as_float(u & 0xffff0000u); }

// fp8 e4m3 helpers (HW packed converts; OCP format on gfx950)
__device__ inline void acc8_fp8(float acc[8], float w, uint2 u) {
    f32x2 c;
    c = __builtin_amdgcn_cvt_pk_f32_fp8(u.x, false); acc[0] += w * c[0]; acc[1] += w * c[1];
    c = __builtin_amdgcn_cvt_pk_f32_fp8(u.x, true);  acc[2] += w * c[0]; acc[3] += w * c[1];
    c = __builtin_amdgcn_cvt_pk_f32_fp8(u.y, false); acc[4] += w * c[0]; acc[5] += w * c[1];
    c = __builtin_amdgcn_cvt_pk_f32_fp8(u.y, true);  acc[6] += w * c[0]; acc[7] += w * c[1];
}
__device__ inline uint2 pack_fp8x8(const float o[8]) {
    int t0 = __builtin_amdgcn_cvt_pk_fp8_f32(o[0], o[1], 0, false);
    t0 = __builtin_amdgcn_cvt_pk_fp8_f32(o[2], o[3], t0, true);
    int t1 = __builtin_amdgcn_cvt_pk_fp8_f32(o[4], o[5], 0, false);
    t1 = __builtin_amdgcn_cvt_pk_fp8_f32(o[6], o[7], t1, true);
    uint2 r; r.x = (unsigned)t0; r.y = (unsigned)t1; return r;
}
__device__ inline unsigned char fp8_of(float v) {
    return (unsigned char)(__builtin_amdgcn_cvt_pk_fp8_f32(v, v, 0, false) & 0xff);
}

// ================= fused: edge histograms(+rank) + casts + B-prep =================
// B-prep folds the Chebyshev recursion into the weights: with A = [T0, P(T0), P^2(T0)]
// (instead of [T0, T1, 2P(T1)-T0]), B rows become W'0 = W0 - W2, W'1 = W1, W'2 = 2*W2.
// All prop passes are then PURE gathers (no subtract stream).

constexpr int EB = (NE + 255) / 256;           // 3125
constexpr int XOCT = NN * CI / 8;              // 100000 octets in x
constexpr int HOCT = NN * CO / 8;              // 400000 octets in h0
constexpr int CB = (XOCT + HOCT + 255) / 256;  // 1954

__global__ void __launch_bounds__(256) k_deg_cast_prep(
    const int* __restrict__ src, const int* __restrict__ dst, const float* __restrict__ ew,
    float* __restrict__ deg, int* __restrict__ count, unsigned short* __restrict__ rank,
    const float* __restrict__ x, const float* __restrict__ h0,
    __bf16* __restrict__ x_bf, __bf16* __restrict__ h0_bf, unsigned char* __restrict__ h0_f8,
    const float* __restrict__ Wx, const float* __restrict__ Wh,
    const float* __restrict__ bx, const float* __restrict__ bh,
    bf16x8* __restrict__ BfragZR, bf16x8* __restrict__ BfragHT, float* __restrict__ biasC) {
    int b = blockIdx.x;
    if (b < EB) {
        int e = b * 256 + threadIdx.x;
        if (e >= NE) return;
        int s = src[e], d = dst[e];
        float w = (s == d) ? 0.f : ew[e];
        atomicAdd(&deg[s], w);
        rank[e] = (unsigned short)atomicAdd(&count[d], 1);
    } else if (b < EB + CB) {
        int t = (b - EB) * 256 + threadIdx.x;  // octet index
        if (t < XOCT) {
            const float* sp = x + (size_t)t * 8;
            float4 a = *(const float4*)sp;
            float4 c = *(const float4*)(sp + 4);
            bf16x8 o;
            o[0] = (__bf16)a.x; o[1] = (__bf16)a.y; o[2] = (__bf16)a.z; o[3] = (__bf16)a.w;
            o[4] = (__bf16)c.x; o[5] = (__bf16)c.y; o[6] = (__bf16)c.z; o[7] = (__bf16)c.w;
            *(bf16x8*)(x_bf + (size_t)t * 8) = o;
        } else if (t < XOCT + HOCT) {
            int u = t - XOCT;
            const float* sp = h0 + (size_t)u * 8;
            float4 a = *(const float4*)sp;
            float4 c = *(const float4*)(sp + 4);
            bf16x8 o;
            o[0] = (__bf16)a.x; o[1] = (__bf16)a.y; o[2] = (__bf16)a.z; o[3] = (__bf16)a.w;
            o[4] = (__bf16)c.x; o[5] = (__bf16)c.y; o[6] = (__bf16)c.z; o[7] = (__bf16)c.w;
            *(bf16x8*)(h0_bf + (size_t)u * 8) = o;
            float f[8] = {a.x, a.y, a.z, a.w, c.x, c.y, c.z, c.w};
            *(uint2*)(h0_f8 + (size_t)u * 8) = pack_fp8x8(f);
        }
    } else {
        int tid = (b - EB - CB) * 256 + threadIdx.x;
        if (tid < 6144) {
            int e = tid, gate, n, kk, l;
            if (e < 4096) {
                int t = e >> 9, rem = e & 511;
                kk = rem >> 6; l = rem & 63;
                n = t * 16 + (l & 15);
                gate = n >> 6;
            } else {
                int e2 = e - 4096;
                int t = e2 >> 9, rem = e2 & 511;
                kk = rem >> 6; l = rem & 63;
                n = t * 16 + (l & 15);
                gate = 2;
            }
            int co = n & 63;
            int k0 = kk * 32 + (l >> 4) * 8;
            bf16x8 f;
#pragma unroll
            for (int j = 0; j < 8; j++) {
                int k = k0 + j;
                float w = 0.f;
                if (k < 48) {
                    int kb = k >> 4, ci = k & 15;
                    const float* Wg = Wx + gate * 3 * 16 * 64;
                    float w0 = Wg[(kb * 16 + ci) * 64 + co];
                    if (kb == 0)      w = w0 - Wg[(2 * 16 + ci) * 64 + co];
                    else if (kb == 1) w = w0;
                    else              w = 2.f * w0;
                } else if (k < 240) {
                    int kh = k - 48, kb = kh >> 6, ci = kh & 63;
                    const float* Wg = Wh + gate * 3 * 64 * 64;
                    float w0 = Wg[(kb * 64 + ci) * 64 + co];
                    if (kb == 0)      w = w0 - Wg[(2 * 64 + ci) * 64 + co];
                    else if (kb == 1) w = w0;
                    else              w = 2.f * w0;
                }
                f[j] = (__bf16)w;
            }
            if (e < 4096) BfragZR[e] = f; else BfragHT[e - 4096] = f;
        } else if (tid < 6144 + 192) {
            int i = tid - 6144;
            biasC[i] = bx[i] + bh[i];
        }
    }
}

// ============================= scan =============================

__global__ void k_scan1(const int* __restrict__ count, int* __restrict__ S, int* __restrict__ bsums) {
    __shared__ int ts[256];
    int tid = threadIdx.x;
    int base = blockIdx.x * 1024;
    int vals[4]; int s = 0;
#pragma unroll
    for (int j = 0; j < 4; j++) {
        int idx = base + tid * 4 + j;
        int v = (idx < NN) ? count[idx] : 0;
        s += v; vals[j] = s;
    }
    ts[tid] = s;
    __syncthreads();
    for (int off = 1; off < 256; off <<= 1) {
        int v = (tid >= off) ? ts[tid - off] : 0;
        __syncthreads();
        ts[tid] += v;
        __syncthreads();
    }
    int prev = (tid > 0) ? ts[tid - 1] : 0;
#pragma unroll
    for (int j = 0; j < 4; j++) {
        int idx = base + tid * 4 + j;
        if (idx < NN) S[idx] = vals[j] + prev;
    }
    if (tid == 255) bsums[blockIdx.x] = ts[255];
}

// merged scan2+scan3: chunk prefix is block-uniform (each 256-block sits in one 1024-chunk)
__global__ void k_scan23(const int* __restrict__ S, const int* __restrict__ bsums,
                         int* __restrict__ rowptr, float* __restrict__ deg) {
    int i = blockIdx.x * 256 + threadIdx.x;
    if (i >= NN) return;
    int chunk = blockIdx.x >> 2;   // uniform across the block
    int pre = 0;
    for (int j = 0; j < chunk; j++) pre += bsums[j];
    int tot = S[i] + pre;
    rowptr[i + 1] = tot;
    if (i == 0) rowptr[0] = 0;
    float d = deg[i];
    deg[i] = (d > 0.f) ? (1.f / sqrtf(d)) : 0.f;
}

// atomic-free placement; meta = u16 src | bf16(dinv[src]*w) in high 16 bits (4B/edge)
__global__ void k_place(const int* __restrict__ src, const int* __restrict__ dst,
                        const float* __restrict__ ew, const unsigned short* __restrict__ rank,
                        const float* __restrict__ dinv, const int* __restrict__ rowptr,
                        unsigned* __restrict__ csr_ew) {
    int e = blockIdx.x * 256 + threadIdx.x;
    if (e >= NE) return;
    int s = src[e], d = dst[e];
    float w = (s == d) ? 0.f : ew[e];
    float wp = dinv[s] * w;
    __bf16 wb = (__bf16)wp;
    unsigned short ub = __builtin_bit_cast(unsigned short, wb);
    csr_ew[rowptr[d] + rank[e]] = (unsigned)s | ((unsigned)ub << 16);
}

// ============================= propagation bodies (pure) =============================
// out[n] = -dinv[n] * sum_{e in row n} w'_e * v[src_e]

// C=64, fp8 gather: 8 edges in flight, 8 lanes x 8B = 64B row (1 line/edge).
__device__ inline void prop64_body(int n, int lane,
                                   const unsigned char* __restrict__ v8,
                                   const float* __restrict__ dinv,
                                   const int* __restrict__ rowptr,
                                   const unsigned* __restrict__ ew,
                                   __bf16* __restrict__ out_bf,
                                   unsigned char* __restrict__ out_f8) {
    int j = lane >> 3, cg = lane & 7;
    int beg = rowptr[n], end = rowptr[n + 1];
    float acc[8] = {0.f, 0.f, 0.f, 0.f, 0.f, 0.f, 0.f, 0.f};
    for (int e = beg + j; e < end; e += 8) {
        unsigned p = ew[e];
        float w = bhi(p);
        int s = p & 0xffff;
        uint2 u = *(const uint2*)(v8 + (size_t)s * 64 + cg * 8);
        acc8_fp8(acc, w, u);
    }
#pragma unroll
    for (int m = 8; m <= 32; m <<= 1) {
#pragma unroll
        for (int i = 0; i < 8; i++) acc[i] += __shfl_xor(acc[i], m, 64);
    }
    if (lane < 8) {
        float f = -dinv[n];
        float o[8];
#pragma unroll
        for (int i = 0; i < 8; i++) o[i] = f * acc[i];
        bf16x8 st;
#pragma unroll
        for (int i = 0; i < 8; i++) st[i] = (__bf16)o[i];
        *(bf16x8*)(out_bf + (size_t)n * 64 + lane * 8) = st;
        if (out_f8) *(uint2*)(out_f8 + (size_t)n * 64 + lane * 8) = pack_fp8x8(o);
    }
}

// C=16 bf16 gather (32B rows): 32 edges in flight.
__device__ inline void prop16_body(int n, int lane,
                                   const __bf16* __restrict__ v,
                                   const float* __restrict__ dinv,
                                   const int* __restrict__ rowptr,
                                   const unsigned* __restrict__ ew, __bf16* __restrict__ out) {
    int j = lane >> 1, cg = lane & 1;
    int beg = rowptr[n], end = rowptr[n + 1];
    float acc[8] = {0.f, 0.f, 0.f, 0.f, 0.f, 0.f, 0.f, 0.f};
    for (int e = beg + j; e < end; e += 32) {
        unsigned p = ew[e];
        float w = bhi(p);
        int s = p & 0xffff;
        uint4 u = *(const uint4*)((const char*)v + ((size_t)s * 32 + cg * 16));
        acc[0] += w * blo(u.x); acc[1] += w * bhi(u.x);
        acc[2] += w * blo(u.y); acc[3] += w * bhi(u.y);
        acc[4] += w * blo(u.z); acc[5] += w * bhi(u.z);
        acc[6] += w * blo(u.w); acc[7] += w * bhi(u.w);
    }
#pragma unroll
    for (int m = 2; m <= 32; m <<= 1) {
#pragma unroll
        for (int i = 0; i < 8; i++) acc[i] += __shfl_xor(acc[i], m, 64);
    }
    if (lane < 2) {
        float f = -dinv[n];
        bf16x8 st;
#pragma unroll
        for (int i = 0; i < 8; i++) st[i] = (__bf16)(f * acc[i]);
        *(bf16x8*)(out + (size_t)n * 16 + lane * 8) = st;
    }
}

// fused stage: waves [0,NN) do h-prop (C=64 fp8), waves [NN,2NN) do x-prop (C=16 bf16)
__global__ void __launch_bounds__(256) k_stage(
    const unsigned char* __restrict__ vh8, const __bf16* __restrict__ vx,
    const float* __restrict__ dinv,
    const int* __restrict__ rowptr, const unsigned* __restrict__ ew,
    __bf16* __restrict__ outh_bf, unsigned char* __restrict__ outh_f8,
    __bf16* __restrict__ outx) {
    int gw = blockIdx.x * 4 + (threadIdx.x >> 6);
    int lane = threadIdx.x & 63;
    if (gw < NN) prop64_body(gw, lane, vh8, dinv, rowptr, ew, outh_bf, outh_f8);
    else if (gw < 2 * NN) prop16_body(gw - NN, lane, vx, dinv, rowptr, ew, outx);
}

__global__ void __launch_bounds__(256) k_prop64(
    const unsigned char* __restrict__ v8, const float* __restrict__ dinv,
    const int* __restrict__ rowptr, const unsigned* __restrict__ ew,
    __bf16* __restrict__ out_bf, unsigned char* __restrict__ out_f8) {
    int n = blockIdx.x * 4 + (threadIdx.x >> 6);
    if (n >= NN) return;
    prop64_body(n, threadIdx.x & 63, v8, dinv, rowptr, ew, out_bf, out_f8);
}

// ============================= MFMA dense gates =============================
// Logical A row (K=256): [x(16)|Px(16)|P2x(16)|H(64)|PH(64)|P2H(64)|pad(16)], bf16 flat.

__device__ inline bf16x8 load_a_bf(int c, int m,
                                   const __bf16* __restrict__ xb, const __bf16* __restrict__ t1,
                                   const __bf16* __restrict__ t2, const __bf16* __restrict__ hb,
                                   const __bf16* __restrict__ h1, const __bf16* __restrict__ h2) {
    if (c >= 30) {
        bf16x8 a;
#pragma unroll
        for (int j = 0; j < 8; j++) a[j] = (__bf16)0.f;
        return a;
    }
    if (c < 6) {
        const __bf16* base = (c < 2) ? xb : ((c < 4) ? t1 : t2);
        return *(const bf16x8*)(base + (size_t)m * 16 + (c & 1) * 8);
    }
    int d = c - 6;
    const __bf16* base = (d < 8) ? hb : ((d < 16) ? h1 : h2);
    return *(const bf16x8*)(base + (size_t)m * 64 + (d & 7) * 8);
}

// z and r gates: one wave per 16-node tile, 128 output cols (8 out-tiles).
__global__ void __launch_bounds__(256) k_mfma_zr(
    const __bf16* __restrict__ xb, const __bf16* __restrict__ t1, const __bf16* __restrict__ t2,
    const __bf16* __restrict__ hb, const __bf16* __restrict__ h1, const __bf16* __restrict__ h2,
    const bf16x8* __restrict__ Bfrag, const float* __restrict__ biasC,
    __bf16* __restrict__ z_bf, __bf16* __restrict__ hr_bf, unsigned char* __restrict__ hr_f8) {
    int wv = (blockIdx.x * 256 + threadIdx.x) >> 6;
    if (wv >= NN / 16) return;
    int lane = threadIdx.x & 63;
    int q = lane >> 4, r16 = lane & 15;
    int ma = wv * 16 + r16;
    f32x4 acc[8];
#pragma unroll
    for (int t = 0; t < 8; t++) acc[t] = (f32x4){0.f, 0.f, 0.f, 0.f};
#pragma unroll
    for (int kk = 0; kk < 8; kk++) {
        bf16x8 a = load_a_bf(kk * 4 + q, ma, xb, t1, t2, hb, h1, h2);
#pragma unroll
        for (int t = 0; t < 8; t++)
            acc[t] = __builtin_amdgcn_mfma_f32_16x16x32_bf16(a, Bfrag[(t * 8 + kk) * 64 + lane], acc[t], 0, 0, 0);
    }
    int mbase = wv * 16 + q * 4;
#pragma unroll
    for (int t = 0; t < 8; t++) {
        int co = t * 16 + r16;      // 0..127
        float bias = biasC[co];
        int col = co & 63;
#pragma unroll
        for (int reg = 0; reg < 4; reg++) {
            int mm = mbase + reg;
            float p = acc[t][reg] + bias;
            float s = 1.f / (1.f + __expf(-p));
            if (t < 4) z_bf[(size_t)mm * 64 + col] = (__bf16)s;
            else {
                float hrv = s * (float)hb[(size_t)mm * 64 + col];
                hr_bf[(size_t)mm * 64 + col] = (__bf16)hrv;
                hr_f8[(size_t)mm * 64 + col] = fp8_of(hrv);
            }
        }
    }
}

// htilde gate + GRU combine + fused decoder: wave per 16-node tile.
__global__ void __launch_bounds__(256) k_mfma_ht(
    const __bf16* __restrict__ xb, const __bf16* __restrict__ t1, const __bf16* __restrict__ t2,
    const __bf16* __restrict__ hrb, const __bf16* __restrict__ r1, const __bf16* __restrict__ r2,
    const bf16x8* __restrict__ Bfrag, const float* __restrict__ biasC,
    const __bf16* __restrict__ z_bf, const float* __restrict__ h0,
    const float* __restrict__ Wlin, const float* __restrict__ blin,
    float* __restrict__ hout, float* __restrict__ yout) {
    int wv = (blockIdx.x * 256 + threadIdx.x) >> 6;
    if (wv >= NN / 16) return;
    int lane = threadIdx.x & 63;
    int q = lane >> 4, r16 = lane & 15;
    int ma = wv * 16 + r16;
    f32x4 acc[4];
#pragma unroll
    for (int t = 0; t < 4; t++) acc[t] = (f32x4){0.f, 0.f, 0.f, 0.f};
#pragma unroll
    for (int kk = 0; kk < 8; kk++) {
        bf16x8 a = load_a_bf(kk * 4 + q, ma, xb, t1, t2, hrb, r1, r2);
#pragma unroll
        for (int t = 0; t < 4; t++)
            acc[t] = __builtin_amdgcn_mfma_f32_16x16x32_bf16(a, Bfrag[(t * 8 + kk) * 64 + lane], acc[t], 0, 0, 0);
    }
    int mbase = wv * 16 + q * 4;
    float hbuf[4][4];
#pragma unroll
    for (int t = 0; t < 4; t++) {
        int co = t * 16 + r16;   // 0..63
        float bias = biasC[128 + co];
#pragma unroll
        for (int reg = 0; reg < 4; reg++) {
            int mm = mbase + reg;
            float p = acc[t][reg] + bias;
            float htl = tanhf(p);
            float zv = (float)z_bf[(size_t)mm * 64 + co];
            float h0v = h0[(size_t)mm * 64 + co];
            float hn = zv * h0v + (1.f - zv) * htl;
            hout[(size_t)mm * 64 + co] = hn;
            hbuf[t][reg] = hn;
        }
    }
    // fused y = relu(h) @ Wlin + blin
    float ya[4][DD];
#pragma unroll
    for (int reg = 0; reg < 4; reg++)
#pragma unroll
        for (int d = 0; d < DD; d++) ya[reg][d] = 0.f;
#pragma unroll
    for (int t = 0; t < 4; t++) {
        int cb = (t * 16 + r16) * DD;
        float wl[DD];
#pragma unroll
        for (int d = 0; d < DD; d++) wl[d] = Wlin[cb + d];
#pragma unroll
        for (int reg = 0; reg < 4; reg++) {
            float rh = fmaxf(hbuf[t][reg], 0.f);
#pragma unroll
            for (int d = 0; d < DD; d++) ya[reg][d] += rh * wl[d];
        }
    }
#pragma unroll
    for (int m = 1; m <= 8; m <<= 1) {
#pragma unroll
        for (int reg = 0; reg < 4; reg++)
#pragma unroll
            for (int d = 0; d < DD; d++) ya[reg][d] += __shfl_xor(ya[reg][d], m, 64);
    }
    if (r16 < DD) {
        float b = blin[r16];
#pragma unroll
        for (int reg = 0; reg < 4; reg++) {
            float v = (r16 == 0) ? ya[reg][0] : (r16 == 1) ? ya[reg][1] : (r16 == 2) ? ya[reg][2]
                    : (r16 == 3) ? ya[reg][3] : (r16 == 4) ? ya[reg][4] : (r16 == 5) ? ya[reg][5]
                    : ya[reg][6];
            yout[(size_t)(mbase + reg) * DD + r16] = v + b;
        }
    }
}

// ============================= launch =============================

extern "C" void kernel_launch(void* const* d_in, const int* in_sizes, int n_in,
                              void* d_out, int out_size, void* d_ws, size_t ws_size,
                              hipStream_t stream) {
    (void)in_sizes; (void)n_in; (void)out_size; (void)ws_size;
    const float* x    = (const float*)d_in[0];
    const int*   eidx = (const int*)d_in[1];
    const float* ew   = (const float*)d_in[2];
    const float* h0   = (const float*)d_in[3];
    const float* Wx   = (const float*)d_in[4];
    const float* Wh   = (const float*)d_in[5];
    const float* bx   = (const float*)d_in[6];
    const float* bh   = (const float*)d_in[7];
    const float* Wlin = (const float*)d_in[8];
    const float* blin = (const float*)d_in[9];
    const int* src = eidx;
    const int* dst = eidx + NE;

    char* ws = (char*)d_ws;
    size_t off = 0;
    auto alloc = [&](size_t nbytes) -> void* {
        void* p = ws + off;
        off += (nbytes + 255) & ~(size_t)255;
        return p;
    };
    float*  dinv    = (float*)alloc(NN * 4);        // deg, then dinv in-place
    int*    count   = (int*)alloc(NN * 4);
    int*    S       = (int*)alloc(NN * 4);
    int*    rowptr  = (int*)alloc((NN + 1) * 4);
    int*    bsums   = (int*)alloc(64 * 4);
    unsigned short* rank = (unsigned short*)alloc((size_t)NE * 2);
    unsigned* csr_ew = (unsigned*)alloc((size_t)NE * 4);
    __bf16* x_bf    = (__bf16*)alloc((size_t)NN * CI * 2);
    __bf16* h0_bf   = (__bf16*)alloc((size_t)NN * CO * 2);
    unsigned char* h0_f8 = (unsigned char*)alloc((size_t)NN * CO);
    unsigned char* T1_f8 = (unsigned char*)alloc((size_t)NN * CO);  // P(h0)/P(hr) fp8
    unsigned char* hr_f8 = (unsigned char*)alloc((size_t)NN * CO);
    __bf16* Tx1     = (__bf16*)alloc((size_t)NN * CI * 2);
    __bf16* Tx2     = (__bf16*)alloc((size_t)NN * CI * 2);
    __bf16* Th1     = (__bf16*)alloc((size_t)NN * CO * 2);
    __bf16* Th2     = (__bf16*)alloc((size_t)NN * CO * 2);
    __bf16* hr_bf   = (__bf16*)alloc((size_t)NN * CO * 2);
    __bf16* z_bf    = (__bf16*)alloc((size_t)NN * CO * 2);
    bf16x8* BfragZR = (bf16x8*)alloc(4096 * 16);
    bf16x8* BfragHT = (bf16x8*)alloc(2048 * 16);
    float*  biasC   = (float*)alloc(192 * 4);

    float* hout = (float*)d_out;
    float* yout = hout + (size_t)NN * CO;

    constexpr int NB = (NN + 1023) / 1024;   // scan chunks
    const int NBLK = (NN + 255) / 256;
    const int PROPB = (NN + 3) / 4;          // 4 waves/block, wave per node
    const int STAGEB = (2 * NN + 3) / 4;     // fused h+x stage
    const int GEMMB = (NN / 16 * 64 + 255) / 256;

    hipMemsetAsync(dinv, 0, NN * 4, stream);
    hipMemsetAsync(count, 0, NN * 4, stream);

    k_deg_cast_prep<<<EB + CB + 25, 256, 0, stream>>>(
        src, dst, ew, dinv, count, rank, x, h0, x_bf, h0_bf, h0_f8,
        Wx, Wh, bx, bh, BfragZR, BfragHT, biasC);
    k_scan1<<<NB, 256, 0, stream>>>(count, S, bsums);
    k_scan23<<<NBLK, 256, 0, stream>>>(S, bsums, rowptr, dinv);
    k_place<<<EB, 256, 0, stream>>>(src, dst, ew, rank, dinv, rowptr, csr_ew);

    // stage 1: P(h0) (bf16+fp8), P(x)
    k_stage<<<STAGEB, 256, 0, stream>>>(h0_f8, x_bf, dinv, rowptr, csr_ew, Th1, T1_f8, Tx1);
    // stage 2: P^2(h0), P^2(x)  (pure — recursion folded into B)
    k_stage<<<STAGEB, 256, 0, stream>>>(T1_f8, Tx1, dinv, rowptr, csr_ew, Th2, nullptr, Tx2);

    // z and r gates (r fused into hr = r*h0)
    k_mfma_zr<<<GEMMB, 256, 0, stream>>>(x_bf, Tx1, Tx2, h0_bf, Th1, Th2,
                                         BfragZR, biasC, z_bf, hr_bf, hr_f8);
    // propagate hr: P(hr), P^2(hr)
    k_prop64<<<PROPB, 256, 0, stream>>>(hr_f8, dinv, rowptr, csr_ew, Th1, T1_f8);
    k_prop64<<<PROPB, 256, 0, stream>>>(T1_f8, dinv, rowptr, csr_ew, Th2, nullptr);
    // htilde gate + GRU combine + fused decoder -> h, y
    k_mfma_ht<<<GEMMB, 256, 0, stream>>>(x_bf, Tx1, Tx2, hr_bf, Th1, Th2,
                                         BfragHT, biasC, z_bf, h0, Wlin, blin, hout, yout);
}

// Round 10
// 359.325 us; speedup vs baseline: 1.2677x; 1.0120x over previous
//
#include <hip/hip_runtime.h>

// Problem constants (from reference)
constexpr int NN = 50000;   // nodes
constexpr int NE = 800000;  // edges
constexpr int CI = 16;      // in channels
constexpr int CO = 64;      // out channels
constexpr int DD = 7;       // decoder dim
constexpr int NXCD = 8;     // XCDs on MI355X

typedef __bf16 bf16x8 __attribute__((ext_vector_type(8)));
typedef float  f32x4  __attribute__((ext_vector_type(4)));
typedef float  f32x2  __attribute__((ext_vector_type(2)));

__device__ inline float blo(unsigned u) { return __uint_as_float(u << 16); }
__device__ inline float bhi(unsigned u) { return __uint_as_float(u & 0xffff0000u); }

// physical XCD id (0..7), wave-uniform [measured: learn_hip m09]
__device__ inline unsigned xcc_id() {
    unsigned v;
    asm volatile("s_getreg_b32 %0, hwreg(HW_REG_XCC_ID)" : "=s"(v));
    return v & 7;
}
// L2-local (no sc1 write-through) relaxed atomics — privatized per XCD, so no
// cross-XCD coherence is needed during accumulation; kernel-end release flushes.
__device__ inline int l2_add_ret(int* p, int v) {
    return __hip_atomic_fetch_add(p, v, __ATOMIC_RELAXED, __HIP_MEMORY_SCOPE_WORKGROUP);
}
__device__ inline void l2_add_f(float* p, float v) {
    __hip_atomic_fetch_add(p, v, __ATOMIC_RELAXED, __HIP_MEMORY_SCOPE_WORKGROUP);
}

// fp8 e4m3 helpers (HW packed converts; OCP format on gfx950)
__device__ inline void acc8_fp8(float acc[8], float w, uint2 u) {
    f32x2 c;
    c = __builtin_amdgcn_cvt_pk_f32_fp8(u.x, false); acc[0] += w * c[0]; acc[1] += w * c[1];
    c = __builtin_amdgcn_cvt_pk_f32_fp8(u.x, true);  acc[2] += w * c[0]; acc[3] += w * c[1];
    c = __builtin_amdgcn_cvt_pk_f32_fp8(u.y, false); acc[4] += w * c[0]; acc[5] += w * c[1];
    c = __builtin_amdgcn_cvt_pk_f32_fp8(u.y, true);  acc[6] += w * c[0]; acc[7] += w * c[1];
}
__device__ inline uint2 pack_fp8x8(const float o[8]) {
    int t0 = __builtin_amdgcn_cvt_pk_fp8_f32(o[0], o[1], 0, false);
    t0 = __builtin_amdgcn_cvt_pk_fp8_f32(o[2], o[3], t0, true);
    int t1 = __builtin_amdgcn_cvt_pk_fp8_f32(o[4], o[5], 0, false);
    t1 = __builtin_amdgcn_cvt_pk_fp8_f32(o[6], o[7], t1, true);
    uint2 r; r.x = (unsigned)t0; r.y = (unsigned)t1; return r;
}
__device__ inline unsigned char fp8_of(float v) {
    return (unsigned char)(__builtin_amdgcn_cvt_pk_fp8_f32(v, v, 0, false) & 0xff);
}

// ================= fused: privatized edge histograms + casts + B-prep =================
// B-prep folds the Chebyshev recursion into the weights (A = [T0, P, P^2];
// W'0 = W0 - W2, W'1 = W1, W'2 = 2*W2) so all props are pure gathers.

constexpr int EB = (NE + 255) / 256;           // 3125
constexpr int XOCT = NN * CI / 8;              // 100000 octets in x
constexpr int HOCT = NN * CO / 8;              // 400000 octets in h0
constexpr int CB = (XOCT + HOCT + 255) / 256;  // 1954

__global__ void __launch_bounds__(256) k_deg_cast_prep(
    const int* __restrict__ src, const int* __restrict__ dst, const float* __restrict__ ew,
    float* __restrict__ deg8, int* __restrict__ count8, uint2* __restrict__ erec,
    const float* __restrict__ x, const float* __restrict__ h0,
    __bf16* __restrict__ x_bf, __bf16* __restrict__ h0_bf, unsigned char* __restrict__ h0_f8,
    const float* __restrict__ Wx, const float* __restrict__ Wh,
    const float* __restrict__ bx, const float* __restrict__ bh,
    bf16x8* __restrict__ BfragZR, bf16x8* __restrict__ BfragHT, float* __restrict__ biasC) {
    int b = blockIdx.x;
    if (b < EB) {
        int e = b * 256 + threadIdx.x;
        if (e >= NE) return;
        int s = src[e], d = dst[e];
        float w = (s == d) ? 0.f : ew[e];
        unsigned xc = xcc_id();
        l2_add_f(&deg8[xc * NN + s], w);
        int rk = l2_add_ret(&count8[xc * NN + d], 1);
        __bf16 wb = (__bf16)w;
        unsigned wu = (unsigned)__builtin_bit_cast(unsigned short, wb);
        erec[e] = make_uint2((unsigned)s | ((unsigned)d << 16),
                             ((unsigned)rk & 0xff) | (xc << 8) | (wu << 16));
    } else if (b < EB + CB) {
        int t = (b - EB) * 256 + threadIdx.x;  // octet index
        if (t < XOCT) {
            const float* sp = x + (size_t)t * 8;
            float4 a = *(const float4*)sp;
            float4 c = *(const float4*)(sp + 4);
            bf16x8 o;
            o[0] = (__bf16)a.x; o[1] = (__bf16)a.y; o[2] = (__bf16)a.z; o[3] = (__bf16)a.w;
            o[4] = (__bf16)c.x; o[5] = (__bf16)c.y; o[6] = (__bf16)c.z; o[7] = (__bf16)c.w;
            *(bf16x8*)(x_bf + (size_t)t * 8) = o;
        } else if (t < XOCT + HOCT) {
            int u = t - XOCT;
            const float* sp = h0 + (size_t)u * 8;
            float4 a = *(const float4*)sp;
            float4 c = *(const float4*)(sp + 4);
            bf16x8 o;
            o[0] = (__bf16)a.x; o[1] = (__bf16)a.y; o[2] = (__bf16)a.z; o[3] = (__bf16)a.w;
            o[4] = (__bf16)c.x; o[5] = (__bf16)c.y; o[6] = (__bf16)c.z; o[7] = (__bf16)c.w;
            *(bf16x8*)(h0_bf + (size_t)u * 8) = o;
            float f[8] = {a.x, a.y, a.z, a.w, c.x, c.y, c.z, c.w};
            *(uint2*)(h0_f8 + (size_t)u * 8) = pack_fp8x8(f);
        }
    } else {
        int tid = (b - EB - CB) * 256 + threadIdx.x;
        if (tid < 6144) {
            int e = tid, gate, n, kk, l;
            if (e < 4096) {
                int t = e >> 9, rem = e & 511;
                kk = rem >> 6; l = rem & 63;
                n = t * 16 + (l & 15);
                gate = n >> 6;
            } else {
                int e2 = e - 4096;
                int t = e2 >> 9, rem = e2 & 511;
                kk = rem >> 6; l = rem & 63;
                n = t * 16 + (l & 15);
                gate = 2;
            }
            int co = n & 63;
            int k0 = kk * 32 + (l >> 4) * 8;
            bf16x8 f;
#pragma unroll
            for (int j = 0; j < 8; j++) {
                int k = k0 + j;
                float w = 0.f;
                if (k < 48) {
                    int kb = k >> 4, ci = k & 15;
                    const float* Wg = Wx + gate * 3 * 16 * 64;
                    float w0 = Wg[(kb * 16 + ci) * 64 + co];
                    if (kb == 0)      w = w0 - Wg[(2 * 16 + ci) * 64 + co];
                    else if (kb == 1) w = w0;
                    else              w = 2.f * w0;
                } else if (k < 240) {
                    int kh = k - 48, kb = kh >> 6, ci = kh & 63;
                    const float* Wg = Wh + gate * 3 * 64 * 64;
                    float w0 = Wg[(kb * 64 + ci) * 64 + co];
                    if (kb == 0)      w = w0 - Wg[(2 * 64 + ci) * 64 + co];
                    else if (kb == 1) w = w0;
                    else              w = 2.f * w0;
                }
                f[j] = (__bf16)w;
            }
            if (e < 4096) BfragZR[e] = f; else BfragHT[e - 4096] = f;
        } else if (tid < 6144 + 192) {
            int i = tid - 6144;
            biasC[i] = bx[i] + bh[i];
        }
    }
}

// ============================= scan =============================

__global__ void k_scan1(const int* __restrict__ count8, int* __restrict__ S, int* __restrict__ bsums) {
    __shared__ int ts[256];
    int tid = threadIdx.x;
    int base = blockIdx.x * 1024;
    int vals[4]; int s = 0;
#pragma unroll
    for (int j = 0; j < 4; j++) {
        int idx = base + tid * 4 + j;
        int v = 0;
        if (idx < NN) {
#pragma unroll
            for (int xc = 0; xc < NXCD; xc++) v += count8[xc * NN + idx];
        }
        s += v; vals[j] = s;
    }
    ts[tid] = s;
    __syncthreads();
    for (int off = 1; off < 256; off <<= 1) {
        int v = (tid >= off) ? ts[tid - off] : 0;
        __syncthreads();
        ts[tid] += v;
        __syncthreads();
    }
    int prev = (tid > 0) ? ts[tid - 1] : 0;
#pragma unroll
    for (int j = 0; j < 4; j++) {
        int idx = base + tid * 4 + j;
        if (idx < NN) S[idx] = vals[j] + prev;
    }
    if (tid == 255) bsums[blockIdx.x] = ts[255];
}

// rowptr + per-XCD offsets + dinv
__global__ void k_scan23(const int* __restrict__ S, const int* __restrict__ bsums,
                         const int* __restrict__ count8, const float* __restrict__ deg8,
                         int* __restrict__ rowptr, int* __restrict__ off8,
                         float* __restrict__ dinv) {
    int i = blockIdx.x * 256 + threadIdx.x;
    if (i >= NN) return;
    int chunk = blockIdx.x >> 2;   // uniform across the block
    int pre = 0;
    for (int j = 0; j < chunk; j++) pre += bsums[j];
    int tot = S[i] + pre;
    rowptr[i + 1] = tot;
    if (i == 0) rowptr[0] = 0;
    int c[NXCD]; int ctot = 0;
#pragma unroll
    for (int xc = 0; xc < NXCD; xc++) { c[xc] = count8[xc * NN + i]; ctot += c[xc]; }
    int run = tot - ctot;
#pragma unroll
    for (int xc = 0; xc < NXCD; xc++) { off8[xc * NN + i] = run; run += c[xc]; }
    float dsum = 0.f;
#pragma unroll
    for (int xc = 0; xc < NXCD; xc++) dsum += deg8[xc * NN + i];
    dinv[i] = (dsum > 0.f) ? (1.f / sqrtf(dsum)) : 0.f;
}

// atomic-free placement from edge records; meta = u16 src | bf16(dinv[src]*w)
__global__ void k_place(const uint2* __restrict__ erec, const float* __restrict__ dinv,
                        const int* __restrict__ off8, unsigned* __restrict__ csr_ew) {
    int e = blockIdx.x * 256 + threadIdx.x;
    if (e >= NE) return;
    uint2 r = erec[e];
    int s = r.x & 0xffff, d = r.x >> 16;
    unsigned rk = r.y & 0xff, xc = (r.y >> 8) & 7;
    float w = bhi(r.y);
    float wp = dinv[s] * w;
    __bf16 wb = (__bf16)wp;
    unsigned short ub = __builtin_bit_cast(unsigned short, wb);
    csr_ew[off8[xc * NN + d] + rk] = (unsigned)s | ((unsigned)ub << 16);
}

// ============================= propagation bodies (pure) =============================
// out[n] = -dinv[n] * sum_{e in row n} w'_e * v[src_e]

__device__ inline void prop64_body(int n, int lane,
                                   const unsigned char* __restrict__ v8,
                                   const float* __restrict__ dinv,
                                   const int* __restrict__ rowptr,
                                   const unsigned* __restrict__ ew,
                                   __bf16* __restrict__ out_bf,
                                   unsigned char* __restrict__ out_f8) {
    int j = lane >> 3, cg = lane & 7;
    int beg = rowptr[n], end = rowptr[n + 1];
    float acc[8] = {0.f, 0.f, 0.f, 0.f, 0.f, 0.f, 0.f, 0.f};
    for (int e = beg + j; e < end; e += 8) {
        unsigned p = ew[e];
        float w = bhi(p);
        int s = p & 0xffff;
        uint2 u = *(const uint2*)(v8 + (size_t)s * 64 + cg * 8);
        acc8_fp8(acc, w, u);
    }
#pragma unroll
    for (int m = 8; m <= 32; m <<= 1) {
#pragma unroll
        for (int i = 0; i < 8; i++) acc[i] += __shfl_xor(acc[i], m, 64);
    }
    if (lane < 8) {
        float f = -dinv[n];
        float o[8];
#pragma unroll
        for (int i = 0; i < 8; i++) o[i] = f * acc[i];
        bf16x8 st;
#pragma unroll
        for (int i = 0; i < 8; i++) st[i] = (__bf16)o[i];
        *(bf16x8*)(out_bf + (size_t)n * 64 + lane * 8) = st;
        if (out_f8) *(uint2*)(out_f8 + (size_t)n * 64 + lane * 8) = pack_fp8x8(o);
    }
}

__device__ inline void prop16_body(int n, int lane,
                                   const __bf16* __restrict__ v,
                                   const float* __restrict__ dinv,
                                   const int* __restrict__ rowptr,
                                   const unsigned* __restrict__ ew, __bf16* __restrict__ out) {
    int j = lane >> 1, cg = lane & 1;
    int beg = rowptr[n], end = rowptr[n + 1];
    float acc[8] = {0.f, 0.f, 0.f, 0.f, 0.f, 0.f, 0.f, 0.f};
    for (int e = beg + j; e < end; e += 32) {
        unsigned p = ew[e];
        float w = bhi(p);
        int s = p & 0xffff;
        uint4 u = *(const uint4*)((const char*)v + ((size_t)s * 32 + cg * 16));
        acc[0] += w * blo(u.x); acc[1] += w * bhi(u.x);
        acc[2] += w * blo(u.y); acc[3] += w * bhi(u.y);
        acc[4] += w * blo(u.z); acc[5] += w * bhi(u.z);
        acc[6] += w * blo(u.w); acc[7] += w * bhi(u.w);
    }
#pragma unroll
    for (int m = 2; m <= 32; m <<= 1) {
#pragma unroll
        for (int i = 0; i < 8; i++) acc[i] += __shfl_xor(acc[i], m, 64);
    }
    if (lane < 2) {
        float f = -dinv[n];
        bf16x8 st;
#pragma unroll
        for (int i = 0; i < 8; i++) st[i] = (__bf16)(f * acc[i]);
        *(bf16x8*)(out + (size_t)n * 16 + lane * 8) = st;
    }
}

// fused stage: waves [0,NN) h-prop (C=64 fp8), waves [NN,2NN) x-prop (C=16 bf16)
__global__ void __launch_bounds__(256) k_stage(
    const unsigned char* __restrict__ vh8, const __bf16* __restrict__ vx,
    const float* __restrict__ dinv,
    const int* __restrict__ rowptr, const unsigned* __restrict__ ew,
    __bf16* __restrict__ outh_bf, unsigned char* __restrict__ outh_f8,
    __bf16* __restrict__ outx) {
    int gw = blockIdx.x * 4 + (threadIdx.x >> 6);
    int lane = threadIdx.x & 63;
    if (gw < NN) prop64_body(gw, lane, vh8, dinv, rowptr, ew, outh_bf, outh_f8);
    else if (gw < 2 * NN) prop16_body(gw - NN, lane, vx, dinv, rowptr, ew, outx);
}

__global__ void __launch_bounds__(256) k_prop64(
    const unsigned char* __restrict__ v8, const float* __restrict__ dinv,
    const int* __restrict__ rowptr, const unsigned* __restrict__ ew,
    __bf16* __restrict__ out_bf, unsigned char* __restrict__ out_f8) {
    int n = blockIdx.x * 4 + (threadIdx.x >> 6);
    if (n >= NN) return;
    prop64_body(n, threadIdx.x & 63, v8, dinv, rowptr, ew, out_bf, out_f8);
}

// ============================= MFMA dense gates =============================
// Logical A row (K=256): [x(16)|Px(16)|P2x(16)|H(64)|PH(64)|P2H(64)|pad(16)], bf16 flat.

__device__ inline bf16x8 load_a_bf(int c, int m,
                                   const __bf16* __restrict__ xb, const __bf16* __restrict__ t1,
                                   const __bf16* __restrict__ t2, const __bf16* __restrict__ hb,
                                   const __bf16* __restrict__ h1, const __bf16* __restrict__ h2) {
    if (c >= 30) {
        bf16x8 a;
#pragma unroll
        for (int j = 0; j < 8; j++) a[j] = (__bf16)0.f;
        return a;
    }
    if (c < 6) {
        const __bf16* base = (c < 2) ? xb : ((c < 4) ? t1 : t2);
        return *(const bf16x8*)(base + (size_t)m * 16 + (c & 1) * 8);
    }
    int d = c - 6;
    const __bf16* base = (d < 8) ? hb : ((d < 16) ? h1 : h2);
    return *(const bf16x8*)(base + (size_t)m * 64 + (d & 7) * 8);
}

// z and r gates: one wave per 16-node tile, 128 output cols (8 out-tiles).
__global__ void __launch_bounds__(256) k_mfma_zr(
    const __bf16* __restrict__ xb, const __bf16* __restrict__ t1, const __bf16* __restrict__ t2,
    const __bf16* __restrict__ hb, const __bf16* __restrict__ h1, const __bf16* __restrict__ h2,
    const bf16x8* __restrict__ Bfrag, const float* __restrict__ biasC,
    __bf16* __restrict__ z_bf, __bf16* __restrict__ hr_bf, unsigned char* __restrict__ hr_f8) {
    int wv = (blockIdx.x * 256 + threadIdx.x) >> 6;
    if (wv >= NN / 16) return;
    int lane = threadIdx.x & 63;
    int q = lane >> 4, r16 = lane & 15;
    int ma = wv * 16 + r16;
    f32x4 acc[8];
#pragma unroll
    for (int t = 0; t < 8; t++) acc[t] = (f32x4){0.f, 0.f, 0.f, 0.f};
#pragma unroll
    for (int kk = 0; kk < 8; kk++) {
        bf16x8 a = load_a_bf(kk * 4 + q, ma, xb, t1, t2, hb, h1, h2);
#pragma unroll
        for (int t = 0; t < 8; t++)
            acc[t] = __builtin_amdgcn_mfma_f32_16x16x32_bf16(a, Bfrag[(t * 8 + kk) * 64 + lane], acc[t], 0, 0, 0);
    }
    int mbase = wv * 16 + q * 4;
#pragma unroll
    for (int t = 0; t < 8; t++) {
        int co = t * 16 + r16;      // 0..127
        float bias = biasC[co];
        int col = co & 63;
#pragma unroll
        for (int reg = 0; reg < 4; reg++) {
            int mm = mbase + reg;
            float p = acc[t][reg] + bias;
            float s = 1.f / (1.f + __expf(-p));
            if (t < 4) z_bf[(size_t)mm * 64 + col] = (__bf16)s;
            else {
                float hrv = s * (float)hb[(size_t)mm * 64 + col];
                hr_bf[(size_t)mm * 64 + col] = (__bf16)hrv;
                hr_f8[(size_t)mm * 64 + col] = fp8_of(hrv);
            }
        }
    }
}

// htilde gate + GRU combine + fused decoder: wave per 16-node tile.
__global__ void __launch_bounds__(256) k_mfma_ht(
    const __bf16* __restrict__ xb, const __bf16* __restrict__ t1, const __bf16* __restrict__ t2,
    const __bf16* __restrict__ hrb, const __bf16* __restrict__ r1, const __bf16* __restrict__ r2,
    const bf16x8* __restrict__ Bfrag, const float* __restrict__ biasC,
    const __bf16* __restrict__ z_bf, const float* __restrict__ h0,
    const float* __restrict__ Wlin, const float* __restrict__ blin,
    float* __restrict__ hout, float* __restrict__ yout) {
    int wv = (blockIdx.x * 256 + threadIdx.x) >> 6;
    if (wv >= NN / 16) return;
    int lane = threadIdx.x & 63;
    int q = lane >> 4, r16 = lane & 15;
    int ma = wv * 16 + r16;
    f32x4 acc[4];
#pragma unroll
    for (int t = 0; t < 4; t++) acc[t] = (f32x4){0.f, 0.f, 0.f, 0.f};
#pragma unroll
    for (int kk = 0; kk < 8; kk++) {
        bf16x8 a = load_a_bf(kk * 4 + q, ma, xb, t1, t2, hrb, r1, r2);
#pragma unroll
        for (int t = 0; t < 4; t++)
            acc[t] = __builtin_amdgcn_mfma_f32_16x16x32_bf16(a, Bfrag[(t * 8 + kk) * 64 + lane], acc[t], 0, 0, 0);
    }
    int mbase = wv * 16 + q * 4;
    float hbuf[4][4];
#pragma unroll
    for (int t = 0; t < 4; t++) {
        int co = t * 16 + r16;   // 0..63
        float bias = biasC[128 + co];
#pragma unroll
        for (int reg = 0; reg < 4; reg++) {
            int mm = mbase + reg;
            float p = acc[t][reg] + bias;
            float htl = tanhf(p);
            float zv = (float)z_bf[(size_t)mm * 64 + co];
            float h0v = h0[(size_t)mm * 64 + co];
            float hn = zv * h0v + (1.f - zv) * htl;
            hout[(size_t)mm * 64 + co] = hn;
            hbuf[t][reg] = hn;
        }
    }
    // fused y = relu(h) @ Wlin + blin
    float ya[4][DD];
#pragma unroll
    for (int reg = 0; reg < 4; reg++)
#pragma unroll
        for (int d = 0; d < DD; d++) ya[reg][d] = 0.f;
#pragma unroll
    for (int t = 0; t < 4; t++) {
        int cb = (t * 16 + r16) * DD;
        float wl[DD];
#pragma unroll
        for (int d = 0; d < DD; d++) wl[d] = Wlin[cb + d];
#pragma unroll
        for (int reg = 0; reg < 4; reg++) {
            float rh = fmaxf(hbuf[t][reg], 0.f);
#pragma unroll
            for (int d = 0; d < DD; d++) ya[reg][d] += rh * wl[d];
        }
    }
#pragma unroll
    for (int m = 1; m <= 8; m <<= 1) {
#pragma unroll
        for (int reg = 0; reg < 4; reg++)
#pragma unroll
            for (int d = 0; d < DD; d++) ya[reg][d] += __shfl_xor(ya[reg][d], m, 64);
    }
    if (r16 < DD) {
        float b = blin[r16];
#pragma unroll
        for (int reg = 0; reg < 4; reg++) {
            float v = (r16 == 0) ? ya[reg][0] : (r16 == 1) ? ya[reg][1] : (r16 == 2) ? ya[reg][2]
                    : (r16 == 3) ? ya[reg][3] : (r16 == 4) ? ya[reg][4] : (r16 == 5) ? ya[reg][5]
                    : ya[reg][6];
            yout[(size_t)(mbase + reg) * DD + r16] = v + b;
        }
    }
}

// ============================= launch =============================

extern "C" void kernel_launch(void* const* d_in, const int* in_sizes, int n_in,
                              void* d_out, int out_size, void* d_ws, size_t ws_size,
                              hipStream_t stream) {
    (void)in_sizes; (void)n_in; (void)out_size; (void)ws_size;
    const float* x    = (const float*)d_in[0];
    const int*   eidx = (const int*)d_in[1];
    const float* ew   = (const float*)d_in[2];
    const float* h0   = (const float*)d_in[3];
    const float* Wx   = (const float*)d_in[4];
    const float* Wh   = (const float*)d_in[5];
    const float* bx   = (const float*)d_in[6];
    const float* bh   = (const float*)d_in[7];
    const float* Wlin = (const float*)d_in[8];
    const float* blin = (const float*)d_in[9];
    const int* src = eidx;
    const int* dst = eidx + NE;

    char* ws = (char*)d_ws;
    size_t off = 0;
    auto alloc = [&](size_t nbytes) -> void* {
        void* p = ws + off;
        off += (nbytes + 255) & ~(size_t)255;
        return p;
    };
    float*  deg8    = (float*)alloc((size_t)NXCD * NN * 4);  // per-XCD copies
    int*    count8  = (int*)alloc((size_t)NXCD * NN * 4);    // per-XCD copies
    int*    off8    = (int*)alloc((size_t)NXCD * NN * 4);    // per-XCD row offsets
    float*  dinv    = (float*)alloc(NN * 4);
    int*    S       = (int*)alloc(NN * 4);
    int*    rowptr  = (int*)alloc((NN + 1) * 4);
    int*    bsums   = (int*)alloc(64 * 4);
    uint2*  erec    = (uint2*)alloc((size_t)NE * 8);
    unsigned* csr_ew = (unsigned*)alloc((size_t)NE * 4);
    __bf16* x_bf    = (__bf16*)alloc((size_t)NN * CI * 2);
    __bf16* h0_bf   = (__bf16*)alloc((size_t)NN * CO * 2);
    unsigned char* h0_f8 = (unsigned char*)alloc((size_t)NN * CO);
    unsigned char* T1_f8 = (unsigned char*)alloc((size_t)NN * CO);
    unsigned char* hr_f8 = (unsigned char*)alloc((size_t)NN * CO);
    __bf16* Tx1     = (__bf16*)alloc((size_t)NN * CI * 2);
    __bf16* Tx2     = (__bf16*)alloc((size_t)NN * CI * 2);
    __bf16* Th1     = (__bf16*)alloc((size_t)NN * CO * 2);
    __bf16* Th2     = (__bf16*)alloc((size_t)NN * CO * 2);
    __bf16* hr_bf   = (__bf16*)alloc((size_t)NN * CO * 2);
    __bf16* z_bf    = (__bf16*)alloc((size_t)NN * CO * 2);
    bf16x8* BfragZR = (bf16x8*)alloc(4096 * 16);
    bf16x8* BfragHT = (bf16x8*)alloc(2048 * 16);
    float*  biasC   = (float*)alloc(192 * 4);

    float* hout = (float*)d_out;
    float* yout = hout + (size_t)NN * CO;

    constexpr int NB = (NN + 1023) / 1024;   // scan chunks
    const int NBLK = (NN + 255) / 256;
    const int PROPB = (NN + 3) / 4;          // 4 waves/block, wave per node
    const int STAGEB = (2 * NN + 3) / 4;     // fused h+x stage
    const int GEMMB = (NN / 16 * 64 + 255) / 256;

    hipMemsetAsync(deg8, 0, (size_t)NXCD * NN * 4, stream);
    hipMemsetAsync(count8, 0, (size_t)NXCD * NN * 4, stream);

    k_deg_cast_prep<<<EB + CB + 25, 256, 0, stream>>>(
        src, dst, ew, deg8, count8, erec, x, h0, x_bf, h0_bf, h0_f8,
        Wx, Wh, bx, bh, BfragZR, BfragHT, biasC);
    k_scan1<<<NB, 256, 0, stream>>>(count8, S, bsums);
    k_scan23<<<NBLK, 256, 0, stream>>>(S, bsums, count8, deg8, rowptr, off8, dinv);
    k_place<<<EB, 256, 0, stream>>>(erec, dinv, off8, csr_ew);

    // stage 1: P(h0) (bf16+fp8), P(x)
    k_stage<<<STAGEB, 256, 0, stream>>>(h0_f8, x_bf, dinv, rowptr, csr_ew, Th1, T1_f8, Tx1);
    // stage 2: P^2(h0), P^2(x)  (pure — recursion folded into B)
    k_stage<<<STAGEB, 256, 0, stream>>>(T1_f8, Tx1, dinv, rowptr, csr_ew, Th2, nullptr, Tx2);

    // z and r gates (r fused into hr = r*h0)
    k_mfma_zr<<<GEMMB, 256, 0, stream>>>(x_bf, Tx1, Tx2, h0_bf, Th1, Th2,
                                         BfragZR, biasC, z_bf, hr_bf, hr_f8);
    // propagate hr: P(hr), P^2(hr)
    k_prop64<<<PROPB, 256, 0, stream>>>(hr_f8, dinv, rowptr, csr_ew, Th1, T1_f8);
    k_prop64<<<PROPB, 256, 0, stream>>>(T1_f8, dinv, rowptr, csr_ew, Th2, nullptr);
    // htilde gate + GRU combine + fused decoder -> h, y
    k_mfma_ht<<<GEMMB, 256, 0, stream>>>(x_bf, Tx1, Tx2, hr_bf, Th1, Th2,
                                         BfragHT, biasC, z_bf, h0, Wlin, blin, hout, yout);
}